// Round 7
// baseline (4533.194 us; speedup 1.0000x reference)
//
#include <hip/hip_runtime.h>
#include <math.h>

// ---------------- problem constants (from setup_inputs) ----------------
#define BATCH 2
#define NTOK 256          // 16x16 patch grid
#define INCH 384
#define NP 50176          // 224*224
#define HW 224
#define NPROTO 64
#define EMBD 32

// ---------------- workspace layout (floats) ----------------
#define OFF_FEATS0   0u            // (2,256,256)
#define OFF_FEATS1   131072u       // (2,512,256)
#define OFF_FEATS2   393216u       // (2,1024,256)
#define OFF_FEATS3   917504u       // (2,1024,256)
#define OFF_TOKT     1441792u      // 4 x (2,384,256)
#define OFF_F0       2228224u      // (2,256,64,64)
#define OFF_F1       4325376u      // (2,512,32,32)
#define OFF_F3       5373952u      // (2,1024,8,8)
#define OFF_FUSED    5505024u      // (2,2816,64,64)
#define OFF_PATH64   28573696u     // (2,256,64,64)
#define OFF_PATH224  0u            // (2,256,224,224)  reuses [0,25.7M) after FUSED dead
#define OFF_T1       25690112u     // (2,128,224,224)  reuses FUSED tail + PATH64 after dead
#define OFF_SIMA     0u            // (2,64,224,224)   after PATH224 dead
#define OFF_SIMB     6422528u
#define OFF_EDGE     12845056u     // (2,224,224)
#define OFF_RES      13000000u     // (2,64,224,224)
#define OFF_BGAIN    19422528u     // (2,224,224)
#define OFF_BB       19522880u     // (64)
#define OFF_ACC      19523008u     // [0]=edge sum, [1]=entropy sum
#define OFF_WF       19523072u     // folded head weights (42496 fl) — valid after PATH224 dead

// WF internal layout (floats, relative):
//   [0,4608)       w1f[oc][9]            oc = g*8+j
//   [4608,41472)   w2f[g][ic][oc8][9]
//   [41472,41984)  b1f[oc]
//   [41984,42496)  b2f[oc]

// ---------------- output layout (floats, return order) ----------------
#define O_IBM 0u
#define O_ACT 100352u
#define O_BB  6522880u
#define O_WT  6523008u
#define O_PE  6623360u
#define O_ENT 9834624u

// ======================================================================
// tokens (B,256,384) -> (B,384,256)
__global__ void k_transpose(const float* __restrict__ in, float* __restrict__ out) {
    int idx = blockIdx.x * 256 + threadIdx.x;       // < 196608
    int n = idx & 255;
    int c = (idx >> 8) % INCH;
    int b = idx / (INCH * NTOK);
    out[idx] = in[(size_t)b * INCH * NTOK + (size_t)n * INCH + c];
}

// 1x1 proj: out[b,o,p] = sum_c A[b,c,p]*W[o,c] + bias[o].  block=256 (p), grid=(O,B)
__global__ __launch_bounds__(256) void k_proj(const float* __restrict__ A,
                                              const float* __restrict__ W,
                                              const float* __restrict__ bias,
                                              float* __restrict__ out, int O) {
    int p = threadIdx.x;
    int o = blockIdx.x, b = blockIdx.y;
    const float* a = A + (size_t)b * INCH * NTOK + p;
    const float* w = W + (size_t)o * INCH;
    float acc = bias[o];
    for (int c = 0; c < INCH; ++c) acc = fmaf(a[(size_t)c * NTOK], w[c], acc);
    out[((size_t)b * O + o) * NTOK + p] = acc;
}

// ConvTranspose k==stride, no overlap. W layout (C,O,K,K). grid=(pxChunks,O,B)
__global__ void k_convt(const float* __restrict__ X, const float* __restrict__ W,
                        const float* __restrict__ bias, float* __restrict__ out,
                        int C, int O, int K) {
    int S = 16 * K;
    int p = blockIdx.x * 256 + threadIdx.x;         // < S*S
    int o = blockIdx.y, b = blockIdx.z;
    int yy = p / S, xx = p - yy * S;
    int h = yy / K, i = yy - h * K, w = xx / K, j = xx - w * K;
    const float* Xb = X + (size_t)b * C * 256 + h * 16 + w;
    const float* Wb = W + ((size_t)o * K + i) * K + j;
    size_t wstride = (size_t)O * K * K;
    float acc = bias[o];
    for (int c = 0; c < C; ++c) acc = fmaf(Xb[(size_t)c * 256], Wb[(size_t)c * wstride], acc);
    out[((size_t)b * O + o) * (size_t)(S * S) + p] = acc;
}

// 3x3 stride2 pad1: (2,1024,16,16)->(2,1024,8,8).
// One block per (o,b): 256 thr = 64 px x 4 channel-slices, LDS reduce.
__global__ __launch_bounds__(256) void k_down(const float* __restrict__ X,
                                              const float* __restrict__ W,
                                              const float* __restrict__ bias,
                                              float* __restrict__ out) {
    __shared__ float red[3][64];
    int tid = threadIdx.x;
    int p = tid & 63, s = tid >> 6;
    int o = blockIdx.x, b = blockIdx.y;
    int oh = p >> 3, ow = p & 7;
    int ro[3], co[3];
    float rm[3], cm[3];
#pragma unroll
    for (int i = 0; i < 3; ++i) {
        int sy = oh * 2 + i - 1;                    // -1..15
        rm[i] = (sy >= 0) ? 1.f : 0.f;
        ro[i] = (sy > 0 ? sy : 0) * 16;
        int sx = ow * 2 + i - 1;
        cm[i] = (sx >= 0) ? 1.f : 0.f;
        co[i] = (sx > 0 ? sx : 0);
    }
    const float* Xb = X + ((size_t)b * 1024 + s * 256) * 256;
    const float* Wo = W + (size_t)o * 9216 + (size_t)s * 256 * 9;
    float acc = 0.f;
#pragma unroll 2
    for (int c = 0; c < 256; ++c) {
        const float* xc = Xb + c * 256;
        const float* wc = Wo + c * 9;
        float t[9];
#pragma unroll
        for (int i = 0; i < 3; ++i)
#pragma unroll
            for (int j = 0; j < 3; ++j)
                t[i * 3 + j] = xc[ro[i] + co[j]] * (rm[i] * cm[j]);
        acc = fmaf(t[0], wc[0], fmaf(t[1], wc[1], fmaf(t[2], wc[2],
              fmaf(t[3], wc[3], fmaf(t[4], wc[4], fmaf(t[5], wc[5],
              fmaf(t[6], wc[6], fmaf(t[7], wc[7], fmaf(t[8], wc[8], acc)))))))));
    }
    if (s) red[s - 1][p] = acc;
    __syncthreads();
    if (s == 0) {
        acc += red[0][p] + red[1][p] + red[2][p];
        out[((size_t)b * 1024 + o) * 64 + p] = acc + bias[o];
    }
}

// build fused concat (2,2816,64,64): f0 copy + align-corners bilinear of f1/f2/f3
__global__ void k_fusedcat(const float* __restrict__ f0, const float* __restrict__ f1,
                           const float* __restrict__ f2, const float* __restrict__ f3,
                           float* __restrict__ out) {
    int idx = blockIdx.x * 256 + threadIdx.x;       // < 23068672
    int pos = idx & 4095;
    int bc = idx >> 12;
    int ch = bc % 2816, b = bc / 2816;
    float v;
    if (ch < 256) {
        v = f0[((size_t)(b * 256 + ch)) * 4096 + pos];
    } else {
        const float* src; int sh;
        if (ch < 768)       { src = f1 + ((size_t)(b * 512 + (ch - 256))) * 1024; sh = 32; }
        else if (ch < 1792) { src = f2 + ((size_t)(b * 1024 + (ch - 768))) * 256; sh = 16; }
        else                { src = f3 + ((size_t)(b * 1024 + (ch - 1792))) * 64; sh = 8;  }
        int y = pos >> 6, x = pos & 63;
        float r = (float)(sh - 1) / 63.0f;
        float cy = y * r, cx = x * r;
        int i0 = (int)cy; if (i0 > sh - 2) i0 = sh - 2;
        int j0 = (int)cx; if (j0 > sh - 2) j0 = sh - 2;
        float ty = cy - (float)i0, tx = cx - (float)j0;
        const float* s0 = src + i0 * sh + j0;
        float v00 = s0[0], v01 = s0[1], v10 = s0[sh], v11 = s0[sh + 1];
        float c0 = v00 + ty * (v10 - v00);
        float c1 = v01 + ty * (v11 - v01);
        v = c0 + tx * (c1 - c0);
    }
    out[idx] = v;
}

// fuse 1x1: path64[b,o,p] = relu(sum_c fused[b,c,p]*W[o,c]+bias). OCT outputs/thread.
template <int OCT>
__global__ __launch_bounds__(256) void k_fuse(const float* __restrict__ A,
                                              const float* __restrict__ W,
                                              const float* __restrict__ bias,
                                              float* __restrict__ out) {
    int p = blockIdx.x * 256 + threadIdx.x;         // < 4096
    int o0 = blockIdx.y * OCT, b = blockIdx.z;
    const float* Ab = A + (size_t)b * 2816 * 4096 + p;
    const float* Wb = W + (size_t)o0 * 2816;
    float acc[OCT];
#pragma unroll
    for (int u = 0; u < OCT; ++u) acc[u] = 0.f;
    for (int c = 0; c < 2816; c += 4) {
        float a0 = Ab[(size_t)c * 4096];
        float a1 = Ab[(size_t)(c + 1) * 4096];
        float a2 = Ab[(size_t)(c + 2) * 4096];
        float a3 = Ab[(size_t)(c + 3) * 4096];
#pragma unroll
        for (int u = 0; u < OCT; ++u) {
            const float* w = Wb + (size_t)u * 2816 + c;
            acc[u] = fmaf(a0, w[0], acc[u]);
            acc[u] = fmaf(a1, w[1], acc[u]);
            acc[u] = fmaf(a2, w[2], acc[u]);
            acc[u] = fmaf(a3, w[3], acc[u]);
        }
    }
#pragma unroll
    for (int u = 0; u < OCT; ++u)
        out[((size_t)b * 256 + o0 + u) * 4096 + p] = fmaxf(acc[u] + bias[o0 + u], 0.f);
}

// bilinear align-corners 64x64 -> 224x224, all 512 channels
__global__ void k_resize224(const float* __restrict__ in, float* __restrict__ out) {
    size_t idx = (size_t)blockIdx.x * 256 + threadIdx.x;   // < 25690112
    int pos = (int)(idx % NP);
    size_t bc = idx / NP;
    int y = pos / HW, x = pos - y * HW;
    const float r = (float)(63.0 / 223.0);
    float cy = y * r, cx = x * r;
    int i0 = (int)cy; if (i0 > 62) i0 = 62;
    int j0 = (int)cx; if (j0 > 62) j0 = 62;
    float ty = cy - (float)i0, tx = cx - (float)j0;
    const float* s0 = in + bc * 4096 + i0 * 64 + j0;
    float v00 = s0[0], v01 = s0[1], v10 = s0[64], v11 = s0[65];
    float c0 = v00 + ty * (v10 - v00);
    float c1 = v01 + ty * (v11 - v01);
    out[idx] = c0 + tx * (c1 - c0);
}

// direct-load 3x3 pad1 conv, 2x2 pixel quad per thread, OCT output chans.
// OCT=16 -> 8/2/4 o-passes for conv1/conv2/smooth: halves the input
// re-stream vs OCT=8 (the R6 fetch-bound limiter).
template <int OCT, bool BN, bool RELU>
__global__ __launch_bounds__(256) void k_conv3(const float* __restrict__ in,
                                               const float* __restrict__ W,
                                               const float* __restrict__ bias,
                                               const float* __restrict__ bng,
                                               const float* __restrict__ bnb,
                                               const float* __restrict__ bnm,
                                               const float* __restrict__ bnv,
                                               float* __restrict__ out, int C, int O) {
    int tid = threadIdx.x;
    int tb = blockIdx.x;                    // 49 tiles of 32x32
    int ty = (tb / 7) * 32, tx = (tb % 7) * 32;
    int o0 = blockIdx.y * OCT;
    int b = blockIdx.z;
    int gx = tx + (tid & 15) * 2;           // quad origin (even)
    int gy = ty + (tid >> 4) * 2;

    int roff[4], coff[4];
    float rmsk[4], cmsk[4];
#pragma unroll
    for (int i = 0; i < 4; ++i) {
        int sy = gy + i - 1;
        rmsk[i] = (sy >= 0 && sy < HW) ? 1.f : 0.f;
        roff[i] = min(max(sy, 0), HW - 1) * HW;
        int sx = gx + i - 1;
        cmsk[i] = (sx >= 0 && sx < HW) ? 1.f : 0.f;
        coff[i] = min(max(sx, 0), HW - 1);
    }
    float acc[OCT][4];
#pragma unroll
    for (int u = 0; u < OCT; ++u)
#pragma unroll
        for (int q = 0; q < 4; ++q) acc[u][q] = 0.f;

    const float* ic = in + (size_t)b * C * NP;
    const float* wbase = W + (size_t)o0 * C * 9;
    for (int c = 0; c < C; ++c) {
        float r[4][4];
#pragma unroll
        for (int i = 0; i < 4; ++i) {
            float m = rmsk[i];
#pragma unroll
            for (int j = 0; j < 4; ++j)
                r[i][j] = ic[roff[i] + coff[j]] * (m * cmsk[j]);
        }
        const float* wc = wbase + (size_t)c * 9;
#pragma unroll
        for (int u = 0; u < OCT; ++u) {
            const float* w = wc + (size_t)u * C * 9;
            float w0 = w[0], w1 = w[1], w2 = w[2];
            float w3 = w[3], w4 = w[4], w5 = w[5];
            float w6 = w[6], w7 = w[7], w8 = w[8];
            acc[u][0] = fmaf(r[0][0], w0, fmaf(r[0][1], w1, fmaf(r[0][2], w2,
                        fmaf(r[1][0], w3, fmaf(r[1][1], w4, fmaf(r[1][2], w5,
                        fmaf(r[2][0], w6, fmaf(r[2][1], w7, fmaf(r[2][2], w8, acc[u][0])))))))));
            acc[u][1] = fmaf(r[0][1], w0, fmaf(r[0][2], w1, fmaf(r[0][3], w2,
                        fmaf(r[1][1], w3, fmaf(r[1][2], w4, fmaf(r[1][3], w5,
                        fmaf(r[2][1], w6, fmaf(r[2][2], w7, fmaf(r[2][3], w8, acc[u][1])))))))));
            acc[u][2] = fmaf(r[1][0], w0, fmaf(r[1][1], w1, fmaf(r[1][2], w2,
                        fmaf(r[2][0], w3, fmaf(r[2][1], w4, fmaf(r[2][2], w5,
                        fmaf(r[3][0], w6, fmaf(r[3][1], w7, fmaf(r[3][2], w8, acc[u][2])))))))));
            acc[u][3] = fmaf(r[1][1], w0, fmaf(r[1][2], w1, fmaf(r[1][3], w2,
                        fmaf(r[2][1], w3, fmaf(r[2][2], w4, fmaf(r[2][3], w5,
                        fmaf(r[3][1], w6, fmaf(r[3][2], w7, fmaf(r[3][3], w8, acc[u][3])))))))));
        }
        ic += NP;
    }
    size_t obase = (size_t)b * O * NP + (size_t)gy * HW + gx;
#pragma unroll
    for (int u = 0; u < OCT; ++u) {
        int o = o0 + u;
        float bs = bias[o], sc = 1.f, sh = 0.f;
        if (BN) { sc = bng[o] * rsqrtf(bnv[o] + 1e-5f); sh = bnb[o] - bnm[o] * sc; }
        size_t ob = obase + (size_t)o * NP;
#pragma unroll
        for (int q = 0; q < 4; ++q) {
            float v = acc[u][q] + bs;
            if (BN) v = v * sc + sh;
            if (RELU) v = fmaxf(v, 0.f);
            out[ob + (q >> 1) * HW + (q & 1)] = v;
        }
    }
}

// sim[b,q,pos] = (sum_e pe[b,e,pos]*proto[q,e]) / sqrt(32)
__global__ __launch_bounds__(256) void k_sim(const float* __restrict__ pe,
                                             const float* __restrict__ proto,
                                             float* __restrict__ sim) {
    int idx = blockIdx.x * 256 + threadIdx.x;       // < 100352
    int b = idx / NP, pos = idx - b * NP;
    const float* p = pe + (size_t)b * EMBD * NP + pos;
    float v[EMBD];
#pragma unroll
    for (int e = 0; e < EMBD; ++e) v[e] = p[(size_t)e * NP];
    const float scale = 1.0f / sqrtf(32.0f);
    float* so = sim + (size_t)b * NPROTO * NP + pos;
    for (int q = 0; q < NPROTO; ++q) {
        float acc = 0.f;
#pragma unroll
        for (int e = 0; e < EMBD; ++e) acc = fmaf(v[e], proto[q * EMBD + e], acc);
        so[(size_t)q * NP] = acc * scale;
    }
}

__global__ void k_init(float* acc) { if (threadIdx.x < 8) acc[threadIdx.x] = 0.f; }

__device__ __forceinline__ float block_reduce_sum(float v) {
    __shared__ float sh[4];
#pragma unroll
    for (int off = 32; off > 0; off >>= 1) v += __shfl_down(v, off);
    int lane = threadIdx.x & 63, wv = threadIdx.x >> 6;
    if (lane == 0) sh[wv] = v;
    __syncthreads();
    return (threadIdx.x == 0) ? (sh[0] + sh[1] + sh[2] + sh[3]) : 0.f;
}

// edge map + global sum
__global__ __launch_bounds__(256) void k_edge(const float* __restrict__ pe,
                                              float* __restrict__ edge,
                                              float* __restrict__ acc) {
    int idx = blockIdx.x * 256 + threadIdx.x;       // < 100352
    int b = idx / NP, pos = idx - b * NP;
    int h = pos / HW, w = pos - h * HW;
    int wn = (w < HW - 1) ? w : HW - 2;
    int hn = (h < HW - 1) ? h : HW - 2;
    const float* pb = pe + (size_t)b * EMBD * NP;
    float sx = 0.f, sy = 0.f;
#pragma unroll 4
    for (int e = 0; e < EMBD; ++e) {
        const float* p = pb + (size_t)e * NP;
        sx += fabsf(p[h * HW + wn] - p[h * HW + wn + 1]);
        sy += fabsf(p[hn * HW + w] - p[hn * HW + HW + w]);
    }
    float ev = (sx + sy) * (0.5f / 32.0f);
    edge[idx] = ev;
    float tot = block_reduce_sum(ev);
    if (threadIdx.x == 0) atomicAdd(acc, tot);
}

// one edge-aware smoothing step
__global__ void k_smooth(const float* __restrict__ sin_, const float* __restrict__ edge,
                         const float* __restrict__ acc, float* __restrict__ sout) {
    int idx = blockIdx.x * 256 + threadIdx.x;       // < 6422528
    int pos = idx % NP;
    int bp = idx / NP;
    int b = bp >> 6;
    int h = pos / HW, w = pos - h * HW;
    float mean = acc[0] * (1.0f / 100352.0f);
    float m = (edge[(size_t)b * NP + pos] > mean) ? 1.f : 0.f;
    const float* sc = sin_ + (size_t)bp * NP;
    float s = 0.f;
#pragma unroll
    for (int dy = -1; dy <= 1; ++dy) {
        int yy = h + dy;
        if (yy < 0 || yy >= HW) continue;
#pragma unroll
        for (int dx = -1; dx <= 1; ++dx) {
            int xx = w + dx;
            if (xx < 0 || xx >= HW) continue;
            s += sc[yy * HW + xx];
        }
    }
    float c = sc[pos];
    sout[idx] = m * c + (1.f - m) * (s * (1.0f / 9.0f));
}

// entropy of softmax over prototypes, reduced to acc[1]
__global__ __launch_bounds__(256) void k_entropy(const float* __restrict__ sim,
                                                 float* __restrict__ acc) {
    int idx = blockIdx.x * 256 + threadIdx.x;
    int b = idx / NP, pos = idx - b * NP;
    const float* s = sim + (size_t)b * NPROTO * NP + pos;
    float v[NPROTO];
    float mx = -3.0e38f;
#pragma unroll
    for (int q = 0; q < NPROTO; ++q) { v[q] = s[(size_t)q * NP]; mx = fmaxf(mx, v[q]); }
    float sum = 0.f;
#pragma unroll
    for (int q = 0; q < NPROTO; ++q) { float e = expf(v[q] - mx); v[q] = e; sum += e; }
    float inv = 1.f / sum;
    float ent = 0.f;
#pragma unroll
    for (int q = 0; q < NPROTO; ++q) {
        float a = v[q] * inv;
        ent -= a * logf(a + 1e-8f);
    }
    float tot = block_reduce_sum(ent);
    if (threadIdx.x == 0) atomicAdd(acc + 1, tot);
}

__global__ void k_bb(const float* __restrict__ pb, const float* __restrict__ bs,
                     float* __restrict__ bbuf, float* __restrict__ obb) {
    int t = threadIdx.x;
    if (t < NPROTO) {
        float v = 1.f + tanhf(pb[t]) * bs[0];
        bbuf[t] = v;
        obb[t] = v;
        obb[NPROTO + t] = v;
    }
}

// softmax over prototypes -> act (to d_out) + base_gain
__global__ __launch_bounds__(256) void k_actsm(const float* __restrict__ sim,
                                               const float* __restrict__ bb,
                                               float* __restrict__ act,
                                               float* __restrict__ bgain) {
    int idx = blockIdx.x * 256 + threadIdx.x;
    int b = idx / NP, pos = idx - b * NP;
    const float* s = sim + (size_t)b * NPROTO * NP + pos;
    float v[NPROTO];
    float mx = -3.0e38f;
#pragma unroll
    for (int q = 0; q < NPROTO; ++q) { v[q] = s[(size_t)q * NP]; mx = fmaxf(mx, v[q]); }
    float sum = 0.f;
#pragma unroll
    for (int q = 0; q < NPROTO; ++q) { float e = expf(v[q] - mx); v[q] = e; sum += e; }
    float inv = 1.f / sum;
    float* a = act + (size_t)b * NPROTO * NP + pos;
    float bg = 0.f;
#pragma unroll
    for (int q = 0; q < NPROTO; ++q) {
        float p = v[q] * inv;
        a[(size_t)q * NP] = p;
        bg = fmaf(p, bb[q], bg);
    }
    bgain[idx] = bg;
}

// fold BN into head conv weights/biases.  512 threads total.
__global__ void k_headprep(const float* __restrict__ w1, const float* __restrict__ b1,
                           const float* __restrict__ g1, const float* __restrict__ be1,
                           const float* __restrict__ m1, const float* __restrict__ v1,
                           const float* __restrict__ w2, const float* __restrict__ b2,
                           const float* __restrict__ g2, const float* __restrict__ be2,
                           const float* __restrict__ m2, const float* __restrict__ v2,
                           float* __restrict__ wf) {
    int oc = blockIdx.x * 256 + threadIdx.x;
    if (oc >= 512) return;
    float s1 = g1[oc] * rsqrtf(v1[oc] + 1e-5f);
#pragma unroll
    for (int k = 0; k < 9; ++k) wf[oc * 9 + k] = w1[oc * 9 + k] * s1;
    wf[41472 + oc] = (b1[oc] - m1[oc]) * s1 + be1[oc];
    float s2 = g2[oc] * rsqrtf(v2[oc] + 1e-5f);
    int g = oc >> 3, j = oc & 7;
#pragma unroll
    for (int icc = 0; icc < 8; ++icc)
#pragma unroll
        for (int k = 0; k < 9; ++k)
            wf[4608 + (size_t)g * 576 + icc * 72 + j * 9 + k] = w2[((size_t)oc * 8 + icc) * 9 + k] * s2;
    wf[41984 + oc] = (b2[oc] - m2[oc]) * s2 + be2[oc];
}

// fused 3-layer grouped residual heads, 16x16 out-tile, BN-folded weights,
// padded LDS (23/21/19 strides -> conflict-free). 25.8 KB LDS -> 6 blocks/CU.
__global__ __launch_bounds__(256) void k_heads(
    const float* __restrict__ act, const float* __restrict__ wf,
    const float* __restrict__ w3, const float* __restrict__ b3,
    float* __restrict__ res) {
    __shared__ float sA[22 * 23];           // input region, origin (oy0-3, ox0-3)
    __shared__ float sH1[8][20 * 21];       // h1 region, origin (oy0-2, ox0-2)
    __shared__ float sH2[8][18 * 19];       // h2 region, origin (oy0-1, ox0-1)
    int tid = threadIdx.x;
    int tile = blockIdx.x, g = blockIdx.y, b = blockIdx.z;
    int oy0 = (tile / 14) * 16, ox0 = (tile % 14) * 16;
    const float* ain = act + (size_t)(b * NPROTO + g) * NP;

    for (int i = tid; i < 484; i += 256) {
        int y = i / 22, x = i - y * 22;
        int gy = oy0 - 3 + y, gx = ox0 - 3 + x;
        float v = 0.f;
        if ((unsigned)gy < HW && (unsigned)gx < HW) v = ain[gy * HW + gx];
        sA[y * 23 + x] = v;
    }
    __syncthreads();

    // stage1: h1 = relu(conv3_folded(act)), 20x20
    const float* b1f = wf + 41472 + g * 8;
    for (int i = tid; i < 400; i += 256) {
        int y = i / 20, x = i - y * 20;
        int gy = oy0 - 2 + y, gx = ox0 - 2 + x;
        float keep = ((unsigned)gy < HW && (unsigned)gx < HW) ? 1.f : 0.f;
        const float* s0 = sA + y * 23 + x;
        float r0 = s0[0],  r1 = s0[1],  r2 = s0[2];
        float r3 = s0[23], r4 = s0[24], r5 = s0[25];
        float r6 = s0[46], r7 = s0[47], r8 = s0[48];
#pragma unroll
        for (int j = 0; j < 8; ++j) {
            const float* w = wf + (g * 8 + j) * 9;
            float v = fmaf(r0, w[0], fmaf(r1, w[1], fmaf(r2, w[2],
                      fmaf(r3, w[3], fmaf(r4, w[4], fmaf(r5, w[5],
                      fmaf(r6, w[6], fmaf(r7, w[7], fmaf(r8, w[8], b1f[j])))))))));
            sH1[j][y * 21 + x] = fmaxf(v, 0.f) * keep;
        }
    }
    __syncthreads();

    // stage2: h2 = relu(conv3_folded(h1, 8->8)), 18x18
    const float* w2f = wf + 4608 + (size_t)g * 576;
    const float* b2f = wf + 41984 + g * 8;
    for (int i = tid; i < 324; i += 256) {
        int y = i / 18, x = i - y * 18;
        int gy = oy0 - 1 + y, gx = ox0 - 1 + x;
        float keep = ((unsigned)gy < HW && (unsigned)gx < HW) ? 1.f : 0.f;
        float a[8];
#pragma unroll
        for (int j = 0; j < 8; ++j) a[j] = b2f[j];
#pragma unroll
        for (int icc = 0; icc < 8; ++icc) {
            const float* s0 = &sH1[icc][y * 21 + x];
            float r0 = s0[0],  r1 = s0[1],  r2 = s0[2];
            float r3 = s0[21], r4 = s0[22], r5 = s0[23];
            float r6 = s0[42], r7 = s0[43], r8 = s0[44];
            const float* w = w2f + icc * 72;
#pragma unroll
            for (int j = 0; j < 8; ++j) {
                const float* wj = w + j * 9;
                a[j] = fmaf(r0, wj[0], fmaf(r1, wj[1], fmaf(r2, wj[2],
                       fmaf(r3, wj[3], fmaf(r4, wj[4], fmaf(r5, wj[5],
                       fmaf(r6, wj[6], fmaf(r7, wj[7], fmaf(r8, wj[8], a[j])))))))));
            }
        }
#pragma unroll
        for (int j = 0; j < 8; ++j)
            sH2[j][y * 19 + x] = fmaxf(a[j], 0.f) * keep;
    }
    __syncthreads();

    // stage3: res = conv3(h2, 8->1), 16x16, one px/thread
    {
        int y = tid >> 4, x = tid & 15;
        float accv = b3[g];
#pragma unroll
        for (int icc = 0; icc < 8; ++icc) {
            const float* s0 = &sH2[icc][y * 19 + x];
            const float* w = w3 + (size_t)(g * 8 + icc) * 9;
            accv = fmaf(s0[0],  w[0], fmaf(s0[1],  w[1], fmaf(s0[2],  w[2],
                   fmaf(s0[19], w[3], fmaf(s0[20], w[4], fmaf(s0[21], w[5],
                   fmaf(s0[38], w[6], fmaf(s0[39], w[7], fmaf(s0[40], w[8], accv)))))))));
        }
        res[(size_t)(b * NPROTO + g) * NP + (size_t)(oy0 + y) * HW + (ox0 + x)] = accv;
    }
}

// weighted = sum_g act*res; gain = bgain*(1+tanh(weighted)*rs); ibm = clip
__global__ __launch_bounds__(256) void k_final(const float* __restrict__ act,
                                               const float* __restrict__ res,
                                               const float* __restrict__ bgain,
                                               const float* __restrict__ rscale,
                                               float* __restrict__ owt,
                                               float* __restrict__ oibm) {
    int idx = blockIdx.x * 256 + threadIdx.x;
    int b = idx / NP, pos = idx - b * NP;
    const float* a = act + (size_t)b * NPROTO * NP + pos;
    const float* r = res + (size_t)b * NPROTO * NP + pos;
    float wt = 0.f;
#pragma unroll
    for (int q = 0; q < NPROTO; ++q) wt = fmaf(a[(size_t)q * NP], r[(size_t)q * NP], wt);
    owt[idx] = wt;
    float gn = bgain[idx] * (1.f + tanhf(wt) * rscale[0]);
    gn = fminf(fmaxf(gn, 0.5f), 2.0f);
    oibm[idx] = gn;
}

__global__ void k_entfinal(const float* __restrict__ acc, float* __restrict__ o) {
    if (threadIdx.x == 0) o[0] = acc[1] * (1.0f / 100352.0f);
}

// ======================================================================
extern "C" void kernel_launch(void* const* d_in, const int* in_sizes, int n_in,
                              void* d_out, int out_size, void* d_ws, size_t ws_size,
                              hipStream_t stream) {
    const float* tokens[4] = {(const float*)d_in[0], (const float*)d_in[1],
                              (const float*)d_in[2], (const float*)d_in[3]};
    const float* proj_w[4] = {(const float*)d_in[4], (const float*)d_in[6],
                              (const float*)d_in[8], (const float*)d_in[10]};
    const float* proj_b[4] = {(const float*)d_in[5], (const float*)d_in[7],
                              (const float*)d_in[9], (const float*)d_in[11]};
    const float* up_w0 = (const float*)d_in[12]; const float* up_b0 = (const float*)d_in[13];
    const float* up_w1 = (const float*)d_in[14]; const float* up_b1 = (const float*)d_in[15];
    const float* down_w3 = (const float*)d_in[16]; const float* down_b3 = (const float*)d_in[17];
    const float* fuse_w = (const float*)d_in[18]; const float* fuse_b = (const float*)d_in[19];
    const float* pe_w1 = (const float*)d_in[20]; const float* pe_b1 = (const float*)d_in[21];
    const float* pe_bn_g = (const float*)d_in[22]; const float* pe_bn_b = (const float*)d_in[23];
    const float* pe_bn_m = (const float*)d_in[24]; const float* pe_bn_v = (const float*)d_in[25];
    const float* pe_w2 = (const float*)d_in[26]; const float* pe_b2 = (const float*)d_in[27];
    const float* prototypes = (const float*)d_in[28];
    const float* proto_biases = (const float*)d_in[29];
    const float* bias_scale = (const float*)d_in[30];
    const float* smooth_w = (const float*)d_in[31]; const float* smooth_b = (const float*)d_in[32];
    const float* hw1 = (const float*)d_in[33]; const float* hb1 = (const float*)d_in[34];
    const float* hg1 = (const float*)d_in[35]; const float* hbe1 = (const float*)d_in[36];
    const float* hm1 = (const float*)d_in[37]; const float* hv1 = (const float*)d_in[38];
    const float* hw2 = (const float*)d_in[39]; const float* hb2 = (const float*)d_in[40];
    const float* hg2 = (const float*)d_in[41]; const float* hbe2 = (const float*)d_in[42];
    const float* hm2 = (const float*)d_in[43]; const float* hv2 = (const float*)d_in[44];
    const float* hw3 = (const float*)d_in[45]; const float* hb3 = (const float*)d_in[46];
    const float* rscale = (const float*)d_in[47];
    (void)in_sizes; (void)n_in; (void)out_size; (void)ws_size;

    float* ws = (float*)d_ws;
    float* FEATS[4] = {ws + OFF_FEATS0, ws + OFF_FEATS1, ws + OFF_FEATS2, ws + OFF_FEATS3};
    float* TOKT = ws + OFF_TOKT;
    float* F0 = ws + OFF_F0; float* F1 = ws + OFF_F1; float* F3 = ws + OFF_F3;
    float* FUSED = ws + OFF_FUSED;
    float* PATH64 = ws + OFF_PATH64;
    float* PATH224 = ws + OFF_PATH224;
    float* T1 = ws + OFF_T1;
    float* SIMA = ws + OFF_SIMA; float* SIMB = ws + OFF_SIMB;
    float* EDGE = ws + OFF_EDGE; float* RES = ws + OFF_RES;
    float* BGAIN = ws + OFF_BGAIN; float* BBUF = ws + OFF_BB; float* ACC = ws + OFF_ACC;
    float* WF = ws + OFF_WF;

    float* out = (float*)d_out;
    float* o_ibm = out + O_IBM; float* o_act = out + O_ACT; float* o_bb = out + O_BB;
    float* o_wt = out + O_WT; float* o_pe = out + O_PE; float* o_ent = out + O_ENT;

    const int OCH[4] = {256, 512, 1024, 1024};
    for (int s = 0; s < 4; ++s)
        k_transpose<<<768, 256, 0, stream>>>(tokens[s], TOKT + s * 196608);
    for (int s = 0; s < 4; ++s)
        k_proj<<<dim3(OCH[s], BATCH), 256, 0, stream>>>(TOKT + s * 196608, proj_w[s], proj_b[s],
                                                        FEATS[s], OCH[s]);
    k_convt<<<dim3(16, 256, BATCH), 256, 0, stream>>>(FEATS[0], up_w0, up_b0, F0, 256, 256, 4);
    k_convt<<<dim3(4, 512, BATCH), 256, 0, stream>>>(FEATS[1], up_w1, up_b1, F1, 512, 512, 2);
    k_down<<<dim3(1024, BATCH), 256, 0, stream>>>(FEATS[3], down_w3, down_b3, F3);
    k_fusedcat<<<90112, 256, 0, stream>>>(F0, F1, FEATS[2], F3, FUSED);
    k_fuse<16><<<dim3(16, 16, BATCH), 256, 0, stream>>>(FUSED, fuse_w, fuse_b, PATH64);
    k_resize224<<<100352, 256, 0, stream>>>(PATH64, PATH224);
    k_conv3<16, true, true><<<dim3(49, 8, BATCH), 256, 0, stream>>>(
        PATH224, pe_w1, pe_b1, pe_bn_g, pe_bn_b, pe_bn_m, pe_bn_v, T1, 256, 128);
    k_conv3<16, false, false><<<dim3(49, 2, BATCH), 256, 0, stream>>>(
        T1, pe_w2, pe_b2, nullptr, nullptr, nullptr, nullptr, o_pe, 128, 32);
    k_sim<<<392, 256, 0, stream>>>(o_pe, prototypes, SIMA);
    k_init<<<1, 64, 0, stream>>>(ACC);
    k_edge<<<392, 256, 0, stream>>>(o_pe, EDGE, ACC);
    k_smooth<<<25088, 256, 0, stream>>>(SIMA, EDGE, ACC, SIMB);
    k_smooth<<<25088, 256, 0, stream>>>(SIMB, EDGE, ACC, SIMA);
    k_entropy<<<392, 256, 0, stream>>>(SIMA, ACC);
    k_conv3<16, false, false><<<dim3(49, 4, BATCH), 256, 0, stream>>>(
        SIMA, smooth_w, smooth_b, nullptr, nullptr, nullptr, nullptr, SIMB, 64, 64);
    k_bb<<<1, 64, 0, stream>>>(proto_biases, bias_scale, BBUF, o_bb);
    k_actsm<<<392, 256, 0, stream>>>(SIMB, BBUF, o_act, BGAIN);
    k_headprep<<<2, 256, 0, stream>>>(hw1, hb1, hg1, hbe1, hm1, hv1,
                                      hw2, hb2, hg2, hbe2, hm2, hv2, WF);
    k_heads<<<dim3(196, 64, BATCH), 256, 0, stream>>>(o_act, WF, hw3, hb3, RES);
    k_final<<<392, 256, 0, stream>>>(o_act, RES, BGAIN, rscale, o_wt, o_ibm);
    k_entfinal<<<1, 1, 0, stream>>>(ACC, o_ent);
}

// Round 8
// 3658.292 us; speedup vs baseline: 1.2392x; 1.2392x over previous
//
#include <hip/hip_runtime.h>
#include <math.h>

// ---------------- problem constants ----------------
#define BATCH 2
#define NTOK 256
#define INCH 384
#define NP 50176          // 224*224
#define HW 224
#define NPROTO 64
#define EMBD 32

// ---------------- workspace layout (floats) ----------------
#define OFF_FEATS0   0u
#define OFF_FEATS1   131072u
#define OFF_FEATS2   393216u
#define OFF_FEATS3   917504u
#define OFF_TOKT     1441792u
#define OFF_F0       2228224u
#define OFF_F1       4325376u
#define OFF_F3       5373952u
#define OFF_FUSED    5505024u      // (2,2816,64,64)
#define OFF_PATH64   28573696u     // (2,256,64,64)
#define OFF_P224C    0u            // (2,224,224,256) bf16 = 12.85M floats, over dead FEATS/FUSED-head
#define OFF_T1       25690112u     // (2,128,224,224) fp32
#define OFF_SIMA     0u            // after P224C dead
#define OFF_SIMB     6422528u
#define OFF_EDGE     12845056u
#define OFF_RES      13000000u     // (2,64,224,224) — also reused earlier for WB/SHIFT
#define OFF_WB       13000000u     // conv1 MFMA weight frags: 294912 bf16 = 147456 fl
#define OFF_SHIFT    13200000u     // 128 fp32 folded conv1 bias
#define OFF_BGAIN    19422528u
#define OFF_BB       19522880u
#define OFF_ACC      19523008u
#define OFF_WF       19523072u     // folded head weights (42496 fl)

// ---------------- output layout ----------------
#define O_IBM 0u
#define O_ACT 100352u
#define O_BB  6522880u
#define O_WT  6523008u
#define O_PE  6623360u
#define O_ENT 9834624u

typedef __attribute__((ext_vector_type(8))) short bf16x8;
typedef __attribute__((ext_vector_type(4))) float f32x4;

__device__ __forceinline__ short f2bf(float f) {
    unsigned u = __float_as_uint(f);
    unsigned r = (u + 0x7fffu + ((u >> 16) & 1u)) >> 16;
    return (short)r;
}

// ======================================================================
__global__ void k_transpose(const float* __restrict__ in, float* __restrict__ out) {
    int idx = blockIdx.x * 256 + threadIdx.x;
    int n = idx & 255;
    int c = (idx >> 8) % INCH;
    int b = idx / (INCH * NTOK);
    out[idx] = in[(size_t)b * INCH * NTOK + (size_t)n * INCH + c];
}

__global__ __launch_bounds__(256) void k_proj(const float* __restrict__ A,
                                              const float* __restrict__ W,
                                              const float* __restrict__ bias,
                                              float* __restrict__ out, int O) {
    int p = threadIdx.x;
    int o = blockIdx.x, b = blockIdx.y;
    const float* a = A + (size_t)b * INCH * NTOK + p;
    const float* w = W + (size_t)o * INCH;
    float acc = bias[o];
    for (int c = 0; c < INCH; ++c) acc = fmaf(a[(size_t)c * NTOK], w[c], acc);
    out[((size_t)b * O + o) * NTOK + p] = acc;
}

__global__ void k_convt(const float* __restrict__ X, const float* __restrict__ W,
                        const float* __restrict__ bias, float* __restrict__ out,
                        int C, int O, int K) {
    int S = 16 * K;
    int p = blockIdx.x * 256 + threadIdx.x;
    int o = blockIdx.y, b = blockIdx.z;
    int yy = p / S, xx = p - yy * S;
    int h = yy / K, i = yy - h * K, w = xx / K, j = xx - w * K;
    const float* Xb = X + (size_t)b * C * 256 + h * 16 + w;
    const float* Wb = W + ((size_t)o * K + i) * K + j;
    size_t wstride = (size_t)O * K * K;
    float acc = bias[o];
    for (int c = 0; c < C; ++c) acc = fmaf(Xb[(size_t)c * 256], Wb[(size_t)c * wstride], acc);
    out[((size_t)b * O + o) * (size_t)(S * S) + p] = acc;
}

__global__ __launch_bounds__(256) void k_down(const float* __restrict__ X,
                                              const float* __restrict__ W,
                                              const float* __restrict__ bias,
                                              float* __restrict__ out) {
    __shared__ float red[3][64];
    int tid = threadIdx.x;
    int p = tid & 63, s = tid >> 6;
    int o = blockIdx.x, b = blockIdx.y;
    int oh = p >> 3, ow = p & 7;
    int ro[3], co[3];
    float rm[3], cm[3];
#pragma unroll
    for (int i = 0; i < 3; ++i) {
        int sy = oh * 2 + i - 1;
        rm[i] = (sy >= 0) ? 1.f : 0.f;
        ro[i] = (sy > 0 ? sy : 0) * 16;
        int sx = ow * 2 + i - 1;
        cm[i] = (sx >= 0) ? 1.f : 0.f;
        co[i] = (sx > 0 ? sx : 0);
    }
    const float* Xb = X + ((size_t)b * 1024 + s * 256) * 256;
    const float* Wo = W + (size_t)o * 9216 + (size_t)s * 256 * 9;
    float acc = 0.f;
#pragma unroll 2
    for (int c = 0; c < 256; ++c) {
        const float* xc = Xb + c * 256;
        const float* wc = Wo + c * 9;
        float t[9];
#pragma unroll
        for (int i = 0; i < 3; ++i)
#pragma unroll
            for (int j = 0; j < 3; ++j)
                t[i * 3 + j] = xc[ro[i] + co[j]] * (rm[i] * cm[j]);
        acc = fmaf(t[0], wc[0], fmaf(t[1], wc[1], fmaf(t[2], wc[2],
              fmaf(t[3], wc[3], fmaf(t[4], wc[4], fmaf(t[5], wc[5],
              fmaf(t[6], wc[6], fmaf(t[7], wc[7], fmaf(t[8], wc[8], acc)))))))));
    }
    if (s) red[s - 1][p] = acc;
    __syncthreads();
    if (s == 0) {
        acc += red[0][p] + red[1][p] + red[2][p];
        out[((size_t)b * 1024 + o) * 64 + p] = acc + bias[o];
    }
}

__global__ void k_fusedcat(const float* __restrict__ f0, const float* __restrict__ f1,
                           const float* __restrict__ f2, const float* __restrict__ f3,
                           float* __restrict__ out) {
    int idx = blockIdx.x * 256 + threadIdx.x;
    int pos = idx & 4095;
    int bc = idx >> 12;
    int ch = bc % 2816, b = bc / 2816;
    float v;
    if (ch < 256) {
        v = f0[((size_t)(b * 256 + ch)) * 4096 + pos];
    } else {
        const float* src; int sh;
        if (ch < 768)       { src = f1 + ((size_t)(b * 512 + (ch - 256))) * 1024; sh = 32; }
        else if (ch < 1792) { src = f2 + ((size_t)(b * 1024 + (ch - 768))) * 256; sh = 16; }
        else                { src = f3 + ((size_t)(b * 1024 + (ch - 1792))) * 64; sh = 8;  }
        int y = pos >> 6, x = pos & 63;
        float r = (float)(sh - 1) / 63.0f;
        float cy = y * r, cx = x * r;
        int i0 = (int)cy; if (i0 > sh - 2) i0 = sh - 2;
        int j0 = (int)cx; if (j0 > sh - 2) j0 = sh - 2;
        float ty = cy - (float)i0, tx = cx - (float)j0;
        const float* s0 = src + i0 * sh + j0;
        float v00 = s0[0], v01 = s0[1], v10 = s0[sh], v11 = s0[sh + 1];
        float c0 = v00 + ty * (v10 - v00);
        float c1 = v01 + ty * (v11 - v01);
        v = c0 + tx * (c1 - c0);
    }
    out[idx] = v;
}

template <int OCT>
__global__ __launch_bounds__(256) void k_fuse(const float* __restrict__ A,
                                              const float* __restrict__ W,
                                              const float* __restrict__ bias,
                                              float* __restrict__ out) {
    int p = blockIdx.x * 256 + threadIdx.x;
    int o0 = blockIdx.y * OCT, b = blockIdx.z;
    const float* Ab = A + (size_t)b * 2816 * 4096 + p;
    const float* Wb = W + (size_t)o0 * 2816;
    float acc[OCT];
#pragma unroll
    for (int u = 0; u < OCT; ++u) acc[u] = 0.f;
    for (int c = 0; c < 2816; c += 4) {
        float a0 = Ab[(size_t)c * 4096];
        float a1 = Ab[(size_t)(c + 1) * 4096];
        float a2 = Ab[(size_t)(c + 2) * 4096];
        float a3 = Ab[(size_t)(c + 3) * 4096];
#pragma unroll
        for (int u = 0; u < OCT; ++u) {
            const float* w = Wb + (size_t)u * 2816 + c;
            acc[u] = fmaf(a0, w[0], acc[u]);
            acc[u] = fmaf(a1, w[1], acc[u]);
            acc[u] = fmaf(a2, w[2], acc[u]);
            acc[u] = fmaf(a3, w[3], acc[u]);
        }
    }
#pragma unroll
    for (int u = 0; u < OCT; ++u)
        out[((size_t)b * 256 + o0 + u) * 4096 + p] = fmaxf(acc[u] + bias[o0 + u], 0.f);
}

// bilinear 64->224, output bf16 CHANNELS-LAST (b,y,x,c) for MFMA conv1
__global__ void k_resize224bf(const float* __restrict__ in, short* __restrict__ out) {
    size_t idx = (size_t)blockIdx.x * 256 + threadIdx.x;   // < 25690112
    int c = (int)(idx & 255);
    size_t p = idx >> 8;                                   // < 100352
    int b = (int)(p / NP);
    int pos = (int)(p - (size_t)b * NP);
    int y = pos / HW, x = pos - y * HW;
    const float r = (float)(63.0 / 223.0);
    float cy = y * r, cx = x * r;
    int i0 = (int)cy; if (i0 > 62) i0 = 62;
    int j0 = (int)cx; if (j0 > 62) j0 = 62;
    float ty = cy - (float)i0, tx = cx - (float)j0;
    const float* s0 = in + ((size_t)(b * 256 + c)) * 4096 + i0 * 64 + j0;
    float v00 = s0[0], v01 = s0[1], v10 = s0[64], v11 = s0[65];
    float c0 = v00 + ty * (v10 - v00);
    float c1 = v01 + ty * (v11 - v01);
    out[idx] = f2bf(c0 + tx * (c1 - c0));
}

// conv1 weight prep: BN-fold + bf16 + MFMA B-fragment order.
// wb[(((chunk*9+tap)*8+nt)*64 + lane)*8 + j] = w[oc][c][tap] * s[oc]
// oc = nt*16 + (lane&15), c = chunk*32 + (lane>>4)*8 + j
__global__ void k_w1prep(const float* __restrict__ w, const float* __restrict__ bias,
                         const float* __restrict__ g, const float* __restrict__ bb,
                         const float* __restrict__ m, const float* __restrict__ v,
                         short* __restrict__ wb, float* __restrict__ shift) {
    int idx = blockIdx.x * 256 + threadIdx.x;      // < 294912
    int j = idx & 7;
    int lane = (idx >> 3) & 63;
    int nt = (idx >> 9) & 7;
    int tc = idx >> 12;                            // chunk*9+tap, < 72
    int tap = tc % 9, chunk = tc / 9;
    int oc = nt * 16 + (lane & 15);
    int c = chunk * 32 + (lane >> 4) * 8 + j;
    float s = g[oc] * rsqrtf(v[oc] + 1e-5f);
    wb[idx] = f2bf(w[((size_t)oc * 256 + c) * 9 + tap] * s);
    if (idx < 128) {
        float si = g[idx] * rsqrtf(v[idx] + 1e-5f);
        shift[idx] = (bias[idx] - m[idx]) * si + bb[idx];
    }
}

// conv1 as implicit GEMM on MFMA bf16: M=px, N=128 oc, K=2304=(9 taps x 256 c).
// Block = 16x8 px tile, 4 waves; wave = 2 m-slices x 8 n-tiles of 16x16x32.
// chunk-outer/tap-inner -> 9-tap halo reuse hits L1 (11.5 KB/block working set).
__global__ __launch_bounds__(256) void k_conv1mfma(const short* __restrict__ X,
                                                   const bf16x8* __restrict__ WB,
                                                   const float* __restrict__ shift,
                                                   float* __restrict__ out) {
    int tid = threadIdx.x;
    int lane = tid & 63, w = tid >> 6;
    int t = blockIdx.x;                            // 392 tiles (14 x 28)
    int b = blockIdx.y;
    int ty0 = (t / 28) * 16, tx0 = (t % 28) * 8;
    int l15 = lane & 15, q = lane >> 4;
    int loc0 = w * 32 + l15;
    int loc1 = loc0 + 16;
    int py0 = ty0 + (loc0 >> 3), px0 = tx0 + (loc0 & 7);
    int py1 = ty0 + (loc1 >> 3), px1 = tx0 + (loc1 & 7);
    int csub = q * 8;
    f32x4 acc0[8], acc1[8];
#pragma unroll
    for (int nt = 0; nt < 8; ++nt) {
        acc0[nt] = (f32x4){0.f, 0.f, 0.f, 0.f};
        acc1[nt] = (f32x4){0.f, 0.f, 0.f, 0.f};
    }
    const short* Xb = X + (size_t)b * NP * 256;
    const bf16x8 zv = {0, 0, 0, 0, 0, 0, 0, 0};
    for (int chunk = 0; chunk < 8; ++chunk) {
        int c0 = chunk * 32 + csub;
#pragma unroll
        for (int tap = 0; tap < 9; ++tap) {
            int dy = tap / 3 - 1, dx = tap % 3 - 1;
            int sy0 = py0 + dy, sx0 = px0 + dx;
            int sy1 = py1 + dy, sx1 = px1 + dx;
            bf16x8 a0 = zv, a1 = zv;
            if ((unsigned)sy0 < HW && (unsigned)sx0 < HW)
                a0 = *(const bf16x8*)(Xb + ((size_t)sy0 * HW + sx0) * 256 + c0);
            if ((unsigned)sy1 < HW && (unsigned)sx1 < HW)
                a1 = *(const bf16x8*)(Xb + ((size_t)sy1 * HW + sx1) * 256 + c0);
            const bf16x8* wbp = WB + (size_t)((chunk * 9 + tap) * 8) * 64 + lane;
#pragma unroll
            for (int nt = 0; nt < 8; ++nt) {
                bf16x8 bf = wbp[nt * 64];
                acc0[nt] = __builtin_amdgcn_mfma_f32_16x16x32_bf16(a0, bf, acc0[nt], 0, 0, 0);
                acc1[nt] = __builtin_amdgcn_mfma_f32_16x16x32_bf16(a1, bf, acc1[nt], 0, 0, 0);
            }
        }
    }
    // epilogue: D col=lane&15 (oc in tile), row=(lane>>4)*4+r (m in slice)
    int m0 = w * 32, m1 = w * 32 + 16;
#pragma unroll
    for (int nt = 0; nt < 8; ++nt) {
        int oc = nt * 16 + l15;
        float sh = shift[oc];
        float* ob = out + ((size_t)(b * 128 + oc)) * NP;
#pragma unroll
        for (int r = 0; r < 4; ++r) {
            int md = q * 4 + r;
            int lm = m0 + md;
            int py = ty0 + (lm >> 3), px = tx0 + (lm & 7);
            ob[py * HW + px] = fmaxf(acc0[nt][r] + sh, 0.f);
            lm = m1 + md;
            py = ty0 + (lm >> 3); px = tx0 + (lm & 7);
            ob[py * HW + px] = fmaxf(acc1[nt][r] + sh, 0.f);
        }
    }
}

// direct-load fp32 3x3 conv (kept for conv2 / smooth)
template <int OCT, bool BN, bool RELU>
__global__ __launch_bounds__(256) void k_conv3(const float* __restrict__ in,
                                               const float* __restrict__ W,
                                               const float* __restrict__ bias,
                                               const float* __restrict__ bng,
                                               const float* __restrict__ bnb,
                                               const float* __restrict__ bnm,
                                               const float* __restrict__ bnv,
                                               float* __restrict__ out, int C, int O) {
    int tid = threadIdx.x;
    int tb = blockIdx.x;
    int ty = (tb / 7) * 32, tx = (tb % 7) * 32;
    int o0 = blockIdx.y * OCT;
    int b = blockIdx.z;
    int gx = tx + (tid & 15) * 2;
    int gy = ty + (tid >> 4) * 2;

    int roff[4], coff[4];
    float rmsk[4], cmsk[4];
#pragma unroll
    for (int i = 0; i < 4; ++i) {
        int sy = gy + i - 1;
        rmsk[i] = (sy >= 0 && sy < HW) ? 1.f : 0.f;
        roff[i] = min(max(sy, 0), HW - 1) * HW;
        int sx = gx + i - 1;
        cmsk[i] = (sx >= 0 && sx < HW) ? 1.f : 0.f;
        coff[i] = min(max(sx, 0), HW - 1);
    }
    float acc[OCT][4];
#pragma unroll
    for (int u = 0; u < OCT; ++u)
#pragma unroll
        for (int qq = 0; qq < 4; ++qq) acc[u][qq] = 0.f;

    const float* ic = in + (size_t)b * C * NP;
    const float* wbase = W + (size_t)o0 * C * 9;
    for (int c = 0; c < C; ++c) {
        float r[4][4];
#pragma unroll
        for (int i = 0; i < 4; ++i) {
            float m = rmsk[i];
#pragma unroll
            for (int j = 0; j < 4; ++j)
                r[i][j] = ic[roff[i] + coff[j]] * (m * cmsk[j]);
        }
        const float* wc = wbase + (size_t)c * 9;
#pragma unroll
        for (int u = 0; u < OCT; ++u) {
            const float* w = wc + (size_t)u * C * 9;
            float w0 = w[0], w1 = w[1], w2 = w[2];
            float w3 = w[3], w4 = w[4], w5 = w[5];
            float w6 = w[6], w7 = w[7], w8 = w[8];
            acc[u][0] = fmaf(r[0][0], w0, fmaf(r[0][1], w1, fmaf(r[0][2], w2,
                        fmaf(r[1][0], w3, fmaf(r[1][1], w4, fmaf(r[1][2], w5,
                        fmaf(r[2][0], w6, fmaf(r[2][1], w7, fmaf(r[2][2], w8, acc[u][0])))))))));
            acc[u][1] = fmaf(r[0][1], w0, fmaf(r[0][2], w1, fmaf(r[0][3], w2,
                        fmaf(r[1][1], w3, fmaf(r[1][2], w4, fmaf(r[1][3], w5,
                        fmaf(r[2][1], w6, fmaf(r[2][2], w7, fmaf(r[2][3], w8, acc[u][1])))))))));
            acc[u][2] = fmaf(r[1][0], w0, fmaf(r[1][1], w1, fmaf(r[1][2], w2,
                        fmaf(r[2][0], w3, fmaf(r[2][1], w4, fmaf(r[2][2], w5,
                        fmaf(r[3][0], w6, fmaf(r[3][1], w7, fmaf(r[3][2], w8, acc[u][2])))))))));
            acc[u][3] = fmaf(r[1][1], w0, fmaf(r[1][2], w1, fmaf(r[1][3], w2,
                        fmaf(r[2][1], w3, fmaf(r[2][2], w4, fmaf(r[2][3], w5,
                        fmaf(r[3][1], w6, fmaf(r[3][2], w7, fmaf(r[3][3], w8, acc[u][3])))))))));
        }
        ic += NP;
    }
    size_t obase = (size_t)b * O * NP + (size_t)gy * HW + gx;
#pragma unroll
    for (int u = 0; u < OCT; ++u) {
        int o = o0 + u;
        float bs = bias[o], sc = 1.f, sh = 0.f;
        if (BN) { sc = bng[o] * rsqrtf(bnv[o] + 1e-5f); sh = bnb[o] - bnm[o] * sc; }
        size_t ob = obase + (size_t)o * NP;
#pragma unroll
        for (int qq = 0; qq < 4; ++qq) {
            float v = acc[u][qq] + bs;
            if (BN) v = v * sc + sh;
            if (RELU) v = fmaxf(v, 0.f);
            out[ob + (qq >> 1) * HW + (qq & 1)] = v;
        }
    }
}

__global__ __launch_bounds__(256) void k_sim(const float* __restrict__ pe,
                                             const float* __restrict__ proto,
                                             float* __restrict__ sim) {
    int idx = blockIdx.x * 256 + threadIdx.x;
    int b = idx / NP, pos = idx - b * NP;
    const float* p = pe + (size_t)b * EMBD * NP + pos;
    float v[EMBD];
#pragma unroll
    for (int e = 0; e < EMBD; ++e) v[e] = p[(size_t)e * NP];
    const float scale = 1.0f / sqrtf(32.0f);
    float* so = sim + (size_t)b * NPROTO * NP + pos;
    for (int q = 0; q < NPROTO; ++q) {
        float acc = 0.f;
#pragma unroll
        for (int e = 0; e < EMBD; ++e) acc = fmaf(v[e], proto[q * EMBD + e], acc);
        so[(size_t)q * NP] = acc * scale;
    }
}

__global__ void k_init(float* acc) { if (threadIdx.x < 8) acc[threadIdx.x] = 0.f; }

__device__ __forceinline__ float block_reduce_sum(float v) {
    __shared__ float sh[4];
#pragma unroll
    for (int off = 32; off > 0; off >>= 1) v += __shfl_down(v, off);
    int lane = threadIdx.x & 63, wv = threadIdx.x >> 6;
    if (lane == 0) sh[wv] = v;
    __syncthreads();
    return (threadIdx.x == 0) ? (sh[0] + sh[1] + sh[2] + sh[3]) : 0.f;
}

__global__ __launch_bounds__(256) void k_edge(const float* __restrict__ pe,
                                              float* __restrict__ edge,
                                              float* __restrict__ acc) {
    int idx = blockIdx.x * 256 + threadIdx.x;
    int b = idx / NP, pos = idx - b * NP;
    int h = pos / HW, w = pos - h * HW;
    int wn = (w < HW - 1) ? w : HW - 2;
    int hn = (h < HW - 1) ? h : HW - 2;
    const float* pb = pe + (size_t)b * EMBD * NP;
    float sx = 0.f, sy = 0.f;
#pragma unroll 4
    for (int e = 0; e < EMBD; ++e) {
        const float* p = pb + (size_t)e * NP;
        sx += fabsf(p[h * HW + wn] - p[h * HW + wn + 1]);
        sy += fabsf(p[hn * HW + w] - p[hn * HW + HW + w]);
    }
    float ev = (sx + sy) * (0.5f / 32.0f);
    edge[idx] = ev;
    float tot = block_reduce_sum(ev);
    if (threadIdx.x == 0) atomicAdd(acc, tot);
}

__global__ void k_smooth(const float* __restrict__ sin_, const float* __restrict__ edge,
                         const float* __restrict__ acc, float* __restrict__ sout) {
    int idx = blockIdx.x * 256 + threadIdx.x;
    int pos = idx % NP;
    int bp = idx / NP;
    int b = bp >> 6;
    int h = pos / HW, w = pos - h * HW;
    float mean = acc[0] * (1.0f / 100352.0f);
    float m = (edge[(size_t)b * NP + pos] > mean) ? 1.f : 0.f;
    const float* sc = sin_ + (size_t)bp * NP;
    float s = 0.f;
#pragma unroll
    for (int dy = -1; dy <= 1; ++dy) {
        int yy = h + dy;
        if (yy < 0 || yy >= HW) continue;
#pragma unroll
        for (int dx = -1; dx <= 1; ++dx) {
            int xx = w + dx;
            if (xx < 0 || xx >= HW) continue;
            s += sc[yy * HW + xx];
        }
    }
    float c = sc[pos];
    sout[idx] = m * c + (1.f - m) * (s * (1.0f / 9.0f));
}

__global__ __launch_bounds__(256) void k_entropy(const float* __restrict__ sim,
                                                 float* __restrict__ acc) {
    int idx = blockIdx.x * 256 + threadIdx.x;
    int b = idx / NP, pos = idx - b * NP;
    const float* s = sim + (size_t)b * NPROTO * NP + pos;
    float v[NPROTO];
    float mx = -3.0e38f;
#pragma unroll
    for (int q = 0; q < NPROTO; ++q) { v[q] = s[(size_t)q * NP]; mx = fmaxf(mx, v[q]); }
    float sum = 0.f;
#pragma unroll
    for (int q = 0; q < NPROTO; ++q) { float e = expf(v[q] - mx); v[q] = e; sum += e; }
    float inv = 1.f / sum;
    float ent = 0.f;
#pragma unroll
    for (int q = 0; q < NPROTO; ++q) {
        float a = v[q] * inv;
        ent -= a * logf(a + 1e-8f);
    }
    float tot = block_reduce_sum(ent);
    if (threadIdx.x == 0) atomicAdd(acc + 1, tot);
}

__global__ void k_bb(const float* __restrict__ pb, const float* __restrict__ bs,
                     float* __restrict__ bbuf, float* __restrict__ obb) {
    int t = threadIdx.x;
    if (t < NPROTO) {
        float v = 1.f + tanhf(pb[t]) * bs[0];
        bbuf[t] = v;
        obb[t] = v;
        obb[NPROTO + t] = v;
    }
}

__global__ __launch_bounds__(256) void k_actsm(const float* __restrict__ sim,
                                               const float* __restrict__ bb,
                                               float* __restrict__ act,
                                               float* __restrict__ bgain) {
    int idx = blockIdx.x * 256 + threadIdx.x;
    int b = idx / NP, pos = idx - b * NP;
    const float* s = sim + (size_t)b * NPROTO * NP + pos;
    float v[NPROTO];
    float mx = -3.0e38f;
#pragma unroll
    for (int q = 0; q < NPROTO; ++q) { v[q] = s[(size_t)q * NP]; mx = fmaxf(mx, v[q]); }
    float sum = 0.f;
#pragma unroll
    for (int q = 0; q < NPROTO; ++q) { float e = expf(v[q] - mx); v[q] = e; sum += e; }
    float inv = 1.f / sum;
    float* a = act + (size_t)b * NPROTO * NP + pos;
    float bg = 0.f;
#pragma unroll
    for (int q = 0; q < NPROTO; ++q) {
        float p = v[q] * inv;
        a[(size_t)q * NP] = p;
        bg = fmaf(p, bb[q], bg);
    }
    bgain[idx] = bg;
}

__global__ void k_headprep(const float* __restrict__ w1, const float* __restrict__ b1,
                           const float* __restrict__ g1, const float* __restrict__ be1,
                           const float* __restrict__ m1, const float* __restrict__ v1,
                           const float* __restrict__ w2, const float* __restrict__ b2,
                           const float* __restrict__ g2, const float* __restrict__ be2,
                           const float* __restrict__ m2, const float* __restrict__ v2,
                           float* __restrict__ wf) {
    int oc = blockIdx.x * 256 + threadIdx.x;
    if (oc >= 512) return;
    float s1 = g1[oc] * rsqrtf(v1[oc] + 1e-5f);
#pragma unroll
    for (int k = 0; k < 9; ++k) wf[oc * 9 + k] = w1[oc * 9 + k] * s1;
    wf[41472 + oc] = (b1[oc] - m1[oc]) * s1 + be1[oc];
    float s2 = g2[oc] * rsqrtf(v2[oc] + 1e-5f);
    int g = oc >> 3, j = oc & 7;
#pragma unroll
    for (int icc = 0; icc < 8; ++icc)
#pragma unroll
        for (int k = 0; k < 9; ++k)
            wf[4608 + (size_t)g * 576 + icc * 72 + j * 9 + k] = w2[((size_t)oc * 8 + icc) * 9 + k] * s2;
    wf[41984 + oc] = (b2[oc] - m2[oc]) * s2 + be2[oc];
}

__global__ __launch_bounds__(256) void k_heads(
    const float* __restrict__ act, const float* __restrict__ wf,
    const float* __restrict__ w3, const float* __restrict__ b3,
    float* __restrict__ res) {
    __shared__ float sA[22 * 23];
    __shared__ float sH1[8][20 * 21];
    __shared__ float sH2[8][18 * 19];
    int tid = threadIdx.x;
    int tile = blockIdx.x, g = blockIdx.y, b = blockIdx.z;
    int oy0 = (tile / 14) * 16, ox0 = (tile % 14) * 16;
    const float* ain = act + (size_t)(b * NPROTO + g) * NP;

    for (int i = tid; i < 484; i += 256) {
        int y = i / 22, x = i - y * 22;
        int gy = oy0 - 3 + y, gx = ox0 - 3 + x;
        float v = 0.f;
        if ((unsigned)gy < HW && (unsigned)gx < HW) v = ain[gy * HW + gx];
        sA[y * 23 + x] = v;
    }
    __syncthreads();

    const float* b1f = wf + 41472 + g * 8;
    for (int i = tid; i < 400; i += 256) {
        int y = i / 20, x = i - y * 20;
        int gy = oy0 - 2 + y, gx = ox0 - 2 + x;
        float keep = ((unsigned)gy < HW && (unsigned)gx < HW) ? 1.f : 0.f;
        const float* s0 = sA + y * 23 + x;
        float r0 = s0[0],  r1 = s0[1],  r2 = s0[2];
        float r3 = s0[23], r4 = s0[24], r5 = s0[25];
        float r6 = s0[46], r7 = s0[47], r8 = s0[48];
#pragma unroll
        for (int j = 0; j < 8; ++j) {
            const float* w = wf + (g * 8 + j) * 9;
            float v = fmaf(r0, w[0], fmaf(r1, w[1], fmaf(r2, w[2],
                      fmaf(r3, w[3], fmaf(r4, w[4], fmaf(r5, w[5],
                      fmaf(r6, w[6], fmaf(r7, w[7], fmaf(r8, w[8], b1f[j])))))))));
            sH1[j][y * 21 + x] = fmaxf(v, 0.f) * keep;
        }
    }
    __syncthreads();

    const float* w2f = wf + 4608 + (size_t)g * 576;
    const float* b2f = wf + 41984 + g * 8;
    for (int i = tid; i < 324; i += 256) {
        int y = i / 18, x = i - y * 18;
        int gy = oy0 - 1 + y, gx = ox0 - 1 + x;
        float keep = ((unsigned)gy < HW && (unsigned)gx < HW) ? 1.f : 0.f;
        float a[8];
#pragma unroll
        for (int j = 0; j < 8; ++j) a[j] = b2f[j];
#pragma unroll
        for (int icc = 0; icc < 8; ++icc) {
            const float* s0 = &sH1[icc][y * 21 + x];
            float r0 = s0[0],  r1 = s0[1],  r2 = s0[2];
            float r3 = s0[21], r4 = s0[22], r5 = s0[23];
            float r6 = s0[42], r7 = s0[43], r8 = s0[44];
            const float* w = w2f + icc * 72;
#pragma unroll
            for (int j = 0; j < 8; ++j) {
                const float* wj = w + j * 9;
                a[j] = fmaf(r0, wj[0], fmaf(r1, wj[1], fmaf(r2, wj[2],
                       fmaf(r3, wj[3], fmaf(r4, wj[4], fmaf(r5, wj[5],
                       fmaf(r6, wj[6], fmaf(r7, wj[7], fmaf(r8, wj[8], a[j])))))))));
            }
        }
#pragma unroll
        for (int j = 0; j < 8; ++j)
            sH2[j][y * 19 + x] = fmaxf(a[j], 0.f) * keep;
    }
    __syncthreads();

    {
        int y = tid >> 4, x = tid & 15;
        float accv = b3[g];
#pragma unroll
        for (int icc = 0; icc < 8; ++icc) {
            const float* s0 = &sH2[icc][y * 19 + x];
            const float* w = w3 + (size_t)(g * 8 + icc) * 9;
            accv = fmaf(s0[0],  w[0], fmaf(s0[1],  w[1], fmaf(s0[2],  w[2],
                   fmaf(s0[19], w[3], fmaf(s0[20], w[4], fmaf(s0[21], w[5],
                   fmaf(s0[38], w[6], fmaf(s0[39], w[7], fmaf(s0[40], w[8], accv)))))))));
        }
        res[(size_t)(b * NPROTO + g) * NP + (size_t)(oy0 + y) * HW + (ox0 + x)] = accv;
    }
}

__global__ __launch_bounds__(256) void k_final(const float* __restrict__ act,
                                               const float* __restrict__ res,
                                               const float* __restrict__ bgain,
                                               const float* __restrict__ rscale,
                                               float* __restrict__ owt,
                                               float* __restrict__ oibm) {
    int idx = blockIdx.x * 256 + threadIdx.x;
    int b = idx / NP, pos = idx - b * NP;
    const float* a = act + (size_t)b * NPROTO * NP + pos;
    const float* r = res + (size_t)b * NPROTO * NP + pos;
    float wt = 0.f;
#pragma unroll
    for (int q = 0; q < NPROTO; ++q) wt = fmaf(a[(size_t)q * NP], r[(size_t)q * NP], wt);
    owt[idx] = wt;
    float gn = bgain[idx] * (1.f + tanhf(wt) * rscale[0]);
    gn = fminf(fmaxf(gn, 0.5f), 2.0f);
    oibm[idx] = gn;
}

__global__ void k_entfinal(const float* __restrict__ acc, float* __restrict__ o) {
    if (threadIdx.x == 0) o[0] = acc[1] * (1.0f / 100352.0f);
}

// ======================================================================
extern "C" void kernel_launch(void* const* d_in, const int* in_sizes, int n_in,
                              void* d_out, int out_size, void* d_ws, size_t ws_size,
                              hipStream_t stream) {
    const float* tokens[4] = {(const float*)d_in[0], (const float*)d_in[1],
                              (const float*)d_in[2], (const float*)d_in[3]};
    const float* proj_w[4] = {(const float*)d_in[4], (const float*)d_in[6],
                              (const float*)d_in[8], (const float*)d_in[10]};
    const float* proj_b[4] = {(const float*)d_in[5], (const float*)d_in[7],
                              (const float*)d_in[9], (const float*)d_in[11]};
    const float* up_w0 = (const float*)d_in[12]; const float* up_b0 = (const float*)d_in[13];
    const float* up_w1 = (const float*)d_in[14]; const float* up_b1 = (const float*)d_in[15];
    const float* down_w3 = (const float*)d_in[16]; const float* down_b3 = (const float*)d_in[17];
    const float* fuse_w = (const float*)d_in[18]; const float* fuse_b = (const float*)d_in[19];
    const float* pe_w1 = (const float*)d_in[20]; const float* pe_b1 = (const float*)d_in[21];
    const float* pe_bn_g = (const float*)d_in[22]; const float* pe_bn_b = (const float*)d_in[23];
    const float* pe_bn_m = (const float*)d_in[24]; const float* pe_bn_v = (const float*)d_in[25];
    const float* pe_w2 = (const float*)d_in[26]; const float* pe_b2 = (const float*)d_in[27];
    const float* prototypes = (const float*)d_in[28];
    const float* proto_biases = (const float*)d_in[29];
    const float* bias_scale = (const float*)d_in[30];
    const float* smooth_w = (const float*)d_in[31]; const float* smooth_b = (const float*)d_in[32];
    const float* hw1 = (const float*)d_in[33]; const float* hb1 = (const float*)d_in[34];
    const float* hg1 = (const float*)d_in[35]; const float* hbe1 = (const float*)d_in[36];
    const float* hm1 = (const float*)d_in[37]; const float* hv1 = (const float*)d_in[38];
    const float* hw2 = (const float*)d_in[39]; const float* hb2 = (const float*)d_in[40];
    const float* hg2 = (const float*)d_in[41]; const float* hbe2 = (const float*)d_in[42];
    const float* hm2 = (const float*)d_in[43]; const float* hv2 = (const float*)d_in[44];
    const float* hw3 = (const float*)d_in[45]; const float* hb3 = (const float*)d_in[46];
    const float* rscale = (const float*)d_in[47];
    (void)in_sizes; (void)n_in; (void)out_size; (void)ws_size;

    float* ws = (float*)d_ws;
    float* FEATS[4] = {ws + OFF_FEATS0, ws + OFF_FEATS1, ws + OFF_FEATS2, ws + OFF_FEATS3};
    float* TOKT = ws + OFF_TOKT;
    float* F0 = ws + OFF_F0; float* F1 = ws + OFF_F1; float* F3 = ws + OFF_F3;
    float* FUSED = ws + OFF_FUSED;
    float* PATH64 = ws + OFF_PATH64;
    short* P224C = (short*)(ws + OFF_P224C);
    short* WB = (short*)(ws + OFF_WB);
    float* SHIFT = ws + OFF_SHIFT;
    float* T1 = ws + OFF_T1;
    float* SIMA = ws + OFF_SIMA; float* SIMB = ws + OFF_SIMB;
    float* EDGE = ws + OFF_EDGE; float* RES = ws + OFF_RES;
    float* BGAIN = ws + OFF_BGAIN; float* BBUF = ws + OFF_BB; float* ACC = ws + OFF_ACC;
    float* WF = ws + OFF_WF;

    float* out = (float*)d_out;
    float* o_ibm = out + O_IBM; float* o_act = out + O_ACT; float* o_bb = out + O_BB;
    float* o_wt = out + O_WT; float* o_pe = out + O_PE; float* o_ent = out + O_ENT;

    const int OCH[4] = {256, 512, 1024, 1024};
    for (int s = 0; s < 4; ++s)
        k_transpose<<<768, 256, 0, stream>>>(tokens[s], TOKT + s * 196608);
    for (int s = 0; s < 4; ++s)
        k_proj<<<dim3(OCH[s], BATCH), 256, 0, stream>>>(TOKT + s * 196608, proj_w[s], proj_b[s],
                                                        FEATS[s], OCH[s]);
    k_convt<<<dim3(16, 256, BATCH), 256, 0, stream>>>(FEATS[0], up_w0, up_b0, F0, 256, 256, 4);
    k_convt<<<dim3(4, 512, BATCH), 256, 0, stream>>>(FEATS[1], up_w1, up_b1, F1, 512, 512, 2);
    k_down<<<dim3(1024, BATCH), 256, 0, stream>>>(FEATS[3], down_w3, down_b3, F3);
    k_fusedcat<<<90112, 256, 0, stream>>>(F0, F1, FEATS[2], F3, FUSED);
    k_fuse<16><<<dim3(16, 16, BATCH), 256, 0, stream>>>(FUSED, fuse_w, fuse_b, PATH64);
    // FUSED now dead: WB/P224C regions safe to write
    k_w1prep<<<1152, 256, 0, stream>>>(pe_w1, pe_b1, pe_bn_g, pe_bn_b, pe_bn_m, pe_bn_v,
                                       WB, SHIFT);
    k_resize224bf<<<100352, 256, 0, stream>>>(PATH64, P224C);
    k_conv1mfma<<<dim3(392, BATCH), 256, 0, stream>>>(P224C, (const bf16x8*)WB, SHIFT, T1);
    k_conv3<4, false, false><<<dim3(49, 8, BATCH), 256, 0, stream>>>(
        T1, pe_w2, pe_b2, nullptr, nullptr, nullptr, nullptr, o_pe, 128, 32);
    k_sim<<<392, 256, 0, stream>>>(o_pe, prototypes, SIMA);
    k_init<<<1, 64, 0, stream>>>(ACC);
    k_edge<<<392, 256, 0, stream>>>(o_pe, EDGE, ACC);
    k_smooth<<<25088, 256, 0, stream>>>(SIMA, EDGE, ACC, SIMB);
    k_smooth<<<25088, 256, 0, stream>>>(SIMB, EDGE, ACC, SIMA);
    k_entropy<<<392, 256, 0, stream>>>(SIMA, ACC);
    k_conv3<8, false, false><<<dim3(49, 8, BATCH), 256, 0, stream>>>(
        SIMA, smooth_w, smooth_b, nullptr, nullptr, nullptr, nullptr, SIMB, 64, 64);
    k_bb<<<1, 64, 0, stream>>>(proto_biases, bias_scale, BBUF, o_bb);
    k_actsm<<<392, 256, 0, stream>>>(SIMB, BBUF, o_act, BGAIN);
    k_headprep<<<2, 256, 0, stream>>>(hw1, hb1, hg1, hbe1, hm1, hv1,
                                      hw2, hb2, hg2, hbe2, hm2, hv2, WF);
    k_heads<<<dim3(196, 64, BATCH), 256, 0, stream>>>(o_act, WF, hw3, hb3, RES);
    k_final<<<392, 256, 0, stream>>>(o_act, RES, BGAIN, rscale, o_wt, o_ibm);
    k_entfinal<<<1, 1, 0, stream>>>(ACC, o_ent);
}

// Round 9
// 3318.682 us; speedup vs baseline: 1.3660x; 1.1023x over previous
//
#include <hip/hip_runtime.h>
#include <math.h>

// ---------------- problem constants ----------------
#define BATCH 2
#define NTOK 256
#define INCH 384
#define NP 50176          // 224*224
#define HW 224
#define NPROTO 64
#define EMBD 32

// ---------------- workspace layout (floats) ----------------
#define OFF_FEATS0   0u
#define OFF_FEATS1   131072u
#define OFF_FEATS2   393216u
#define OFF_FEATS3   917504u
#define OFF_TOKT     1441792u
#define OFF_F0       2228224u
#define OFF_F1       4325376u
#define OFF_F3       5373952u
#define OFF_FUSED    5505024u      // (2,2816,64,64)
#define OFF_PATH64   28573696u     // (2,256,64,64)
#define OFF_P224C    0u            // (2,224,224,256) bf16 = 12.85M floats
#define OFF_T1       25690112u     // (2,128,224,224) fp32
#define OFF_SIMA     0u
#define OFF_SIMB     6422528u
#define OFF_EDGE     12845056u
#define OFF_RES      13000000u
#define OFF_WB       13000000u     // conv1 MFMA weight frags (dead-RES window)
#define OFF_SHIFT    13200000u
#define OFF_BGAIN    19422528u
#define OFF_BB       19522880u
#define OFF_ACC      19523008u
#define OFF_WF       19523072u     // folded head weights (42496 fl)

// ---------------- output layout ----------------
#define O_IBM 0u
#define O_ACT 100352u
#define O_BB  6522880u
#define O_WT  6523008u
#define O_PE  6623360u
#define O_ENT 9834624u

typedef __attribute__((ext_vector_type(8))) short bf16x8;
typedef __attribute__((ext_vector_type(4))) float f32x4;

__device__ __forceinline__ short f2bf(float f) {
    unsigned u = __float_as_uint(f);
    unsigned r = (u + 0x7fffu + ((u >> 16) & 1u)) >> 16;
    return (short)r;
}

// ======================================================================
__global__ void k_transpose(const float* __restrict__ in, float* __restrict__ out) {
    int idx = blockIdx.x * 256 + threadIdx.x;
    int n = idx & 255;
    int c = (idx >> 8) % INCH;
    int b = idx / (INCH * NTOK);
    out[idx] = in[(size_t)b * INCH * NTOK + (size_t)n * INCH + c];
}

__global__ __launch_bounds__(256) void k_proj(const float* __restrict__ A,
                                              const float* __restrict__ W,
                                              const float* __restrict__ bias,
                                              float* __restrict__ out, int O) {
    int p = threadIdx.x;
    int o = blockIdx.x, b = blockIdx.y;
    const float* a = A + (size_t)b * INCH * NTOK + p;
    const float* w = W + (size_t)o * INCH;
    float acc = bias[o];
    for (int c = 0; c < INCH; ++c) acc = fmaf(a[(size_t)c * NTOK], w[c], acc);
    out[((size_t)b * O + o) * NTOK + p] = acc;
}

__global__ void k_convt(const float* __restrict__ X, const float* __restrict__ W,
                        const float* __restrict__ bias, float* __restrict__ out,
                        int C, int O, int K) {
    int S = 16 * K;
    int p = blockIdx.x * 256 + threadIdx.x;
    int o = blockIdx.y, b = blockIdx.z;
    int yy = p / S, xx = p - yy * S;
    int h = yy / K, i = yy - h * K, w = xx / K, j = xx - w * K;
    const float* Xb = X + (size_t)b * C * 256 + h * 16 + w;
    const float* Wb = W + ((size_t)o * K + i) * K + j;
    size_t wstride = (size_t)O * K * K;
    float acc = bias[o];
    for (int c = 0; c < C; ++c) acc = fmaf(Xb[(size_t)c * 256], Wb[(size_t)c * wstride], acc);
    out[((size_t)b * O + o) * (size_t)(S * S) + p] = acc;
}

// 3x3 stride2 pad1: (2,1024,16,16)->(2,1024,8,8).
// Weights staged to LDS once (coalesced 36.9 KB), then c-loop reads
// wave-uniform LDS broadcasts + L2-resident input. 2 ch/iter for ILP.
__global__ __launch_bounds__(256) void k_down(const float* __restrict__ X,
                                              const float* __restrict__ W,
                                              const float* __restrict__ bias,
                                              float* __restrict__ out) {
    __shared__ float wsh[9216];
    __shared__ float red[3][64];
    int tid = threadIdx.x;
    int o = blockIdx.x, b = blockIdx.y;
    const float* Wo = W + (size_t)o * 9216;
    for (int i = tid; i < 9216; i += 256) wsh[i] = Wo[i];
    __syncthreads();
    int p = tid & 63, s = tid >> 6;
    int oh = p >> 3, ow = p & 7;
    int ro[3], co[3];
    float rm[3], cm[3];
#pragma unroll
    for (int i = 0; i < 3; ++i) {
        int sy = oh * 2 + i - 1;
        rm[i] = (sy >= 0) ? 1.f : 0.f;
        ro[i] = (sy > 0 ? sy : 0) * 16;
        int sx = ow * 2 + i - 1;
        cm[i] = (sx >= 0) ? 1.f : 0.f;
        co[i] = (sx > 0 ? sx : 0);
    }
    float msk[9];
#pragma unroll
    for (int i = 0; i < 3; ++i)
#pragma unroll
        for (int j = 0; j < 3; ++j) msk[i * 3 + j] = rm[i] * cm[j];
    const float* Xb = X + ((size_t)b * 1024 + s * 256) * 256;
    const float* wb = wsh + s * 256 * 9;
    float acc0 = 0.f, acc1 = 0.f;
    for (int c = 0; c < 256; c += 2) {
        const float* xc0 = Xb + c * 256;
        const float* xc1 = xc0 + 256;
        const float* wc0 = wb + c * 9;
        const float* wc1 = wc0 + 9;
        float t0[9], t1[9];
#pragma unroll
        for (int i = 0; i < 3; ++i)
#pragma unroll
            for (int j = 0; j < 3; ++j) {
                int k = i * 3 + j, a = ro[i] + co[j];
                t0[k] = xc0[a] * msk[k];
                t1[k] = xc1[a] * msk[k];
            }
#pragma unroll
        for (int k = 0; k < 9; ++k) {
            acc0 = fmaf(t0[k], wc0[k], acc0);
            acc1 = fmaf(t1[k], wc1[k], acc1);
        }
    }
    float acc = acc0 + acc1;
    if (s) red[s - 1][p] = acc;
    __syncthreads();
    if (s == 0) {
        acc += red[0][p] + red[1][p] + red[2][p];
        out[((size_t)b * 1024 + o) * 64 + p] = acc + bias[o];
    }
}

__global__ void k_fusedcat(const float* __restrict__ f0, const float* __restrict__ f1,
                           const float* __restrict__ f2, const float* __restrict__ f3,
                           float* __restrict__ out) {
    int idx = blockIdx.x * 256 + threadIdx.x;
    int pos = idx & 4095;
    int bc = idx >> 12;
    int ch = bc % 2816, b = bc / 2816;
    float v;
    if (ch < 256) {
        v = f0[((size_t)(b * 256 + ch)) * 4096 + pos];
    } else {
        const float* src; int sh;
        if (ch < 768)       { src = f1 + ((size_t)(b * 512 + (ch - 256))) * 1024; sh = 32; }
        else if (ch < 1792) { src = f2 + ((size_t)(b * 1024 + (ch - 768))) * 256; sh = 16; }
        else                { src = f3 + ((size_t)(b * 1024 + (ch - 1792))) * 64; sh = 8;  }
        int y = pos >> 6, x = pos & 63;
        float r = (float)(sh - 1) / 63.0f;
        float cy = y * r, cx = x * r;
        int i0 = (int)cy; if (i0 > sh - 2) i0 = sh - 2;
        int j0 = (int)cx; if (j0 > sh - 2) j0 = sh - 2;
        float ty = cy - (float)i0, tx = cx - (float)j0;
        const float* s0 = src + i0 * sh + j0;
        float v00 = s0[0], v01 = s0[1], v10 = s0[sh], v11 = s0[sh + 1];
        float c0 = v00 + ty * (v10 - v00);
        float c1 = v01 + ty * (v11 - v01);
        v = c0 + tx * (c1 - c0);
    }
    out[idx] = v;
}

template <int OCT>
__global__ __launch_bounds__(256) void k_fuse(const float* __restrict__ A,
                                              const float* __restrict__ W,
                                              const float* __restrict__ bias,
                                              float* __restrict__ out) {
    int p = blockIdx.x * 256 + threadIdx.x;
    int o0 = blockIdx.y * OCT, b = blockIdx.z;
    const float* Ab = A + (size_t)b * 2816 * 4096 + p;
    const float* Wb = W + (size_t)o0 * 2816;
    float acc[OCT];
#pragma unroll
    for (int u = 0; u < OCT; ++u) acc[u] = 0.f;
    for (int c = 0; c < 2816; c += 4) {
        float a0 = Ab[(size_t)c * 4096];
        float a1 = Ab[(size_t)(c + 1) * 4096];
        float a2 = Ab[(size_t)(c + 2) * 4096];
        float a3 = Ab[(size_t)(c + 3) * 4096];
#pragma unroll
        for (int u = 0; u < OCT; ++u) {
            const float* w = Wb + (size_t)u * 2816 + c;
            acc[u] = fmaf(a0, w[0], acc[u]);
            acc[u] = fmaf(a1, w[1], acc[u]);
            acc[u] = fmaf(a2, w[2], acc[u]);
            acc[u] = fmaf(a3, w[3], acc[u]);
        }
    }
#pragma unroll
    for (int u = 0; u < OCT; ++u)
        out[((size_t)b * 256 + o0 + u) * 4096 + p] = fmaxf(acc[u] + bias[o0 + u], 0.f);
}

// bilinear 64->224, output bf16 CHANNELS-LAST (b,y,x,c) for MFMA conv1
__global__ void k_resize224bf(const float* __restrict__ in, short* __restrict__ out) {
    size_t idx = (size_t)blockIdx.x * 256 + threadIdx.x;
    int c = (int)(idx & 255);
    size_t p = idx >> 8;
    int b = (int)(p / NP);
    int pos = (int)(p - (size_t)b * NP);
    int y = pos / HW, x = pos - y * HW;
    const float r = (float)(63.0 / 223.0);
    float cy = y * r, cx = x * r;
    int i0 = (int)cy; if (i0 > 62) i0 = 62;
    int j0 = (int)cx; if (j0 > 62) j0 = 62;
    float ty = cy - (float)i0, tx = cx - (float)j0;
    const float* s0 = in + ((size_t)(b * 256 + c)) * 4096 + i0 * 64 + j0;
    float v00 = s0[0], v01 = s0[1], v10 = s0[64], v11 = s0[65];
    float c0 = v00 + ty * (v10 - v00);
    float c1 = v01 + ty * (v11 - v01);
    out[idx] = f2bf(c0 + tx * (c1 - c0));
}

// conv1 weight prep: BN-fold + bf16 + MFMA B-fragment order.
__global__ void k_w1prep(const float* __restrict__ w, const float* __restrict__ bias,
                         const float* __restrict__ g, const float* __restrict__ bb,
                         const float* __restrict__ m, const float* __restrict__ v,
                         short* __restrict__ wb, float* __restrict__ shift) {
    int idx = blockIdx.x * 256 + threadIdx.x;      // < 294912
    int j = idx & 7;
    int lane = (idx >> 3) & 63;
    int nt = (idx >> 9) & 7;
    int tc = idx >> 12;
    int tap = tc % 9, chunk = tc / 9;
    int oc = nt * 16 + (lane & 15);
    int c = chunk * 32 + (lane >> 4) * 8 + j;
    float s = g[oc] * rsqrtf(v[oc] + 1e-5f);
    wb[idx] = f2bf(w[((size_t)oc * 256 + c) * 9 + tap] * s);
    if (idx < 128) {
        float si = g[idx] * rsqrtf(v[idx] + 1e-5f);
        shift[idx] = (bias[idx] - m[idx]) * si + bb[idx];
    }
}

// conv1 as implicit GEMM on MFMA bf16.
__global__ __launch_bounds__(256) void k_conv1mfma(const short* __restrict__ X,
                                                   const bf16x8* __restrict__ WB,
                                                   const float* __restrict__ shift,
                                                   float* __restrict__ out) {
    int tid = threadIdx.x;
    int lane = tid & 63, w = tid >> 6;
    int t = blockIdx.x;
    int b = blockIdx.y;
    int ty0 = (t / 28) * 16, tx0 = (t % 28) * 8;
    int l15 = lane & 15, q = lane >> 4;
    int loc0 = w * 32 + l15;
    int loc1 = loc0 + 16;
    int py0 = ty0 + (loc0 >> 3), px0 = tx0 + (loc0 & 7);
    int py1 = ty0 + (loc1 >> 3), px1 = tx0 + (loc1 & 7);
    int csub = q * 8;
    f32x4 acc0[8], acc1[8];
#pragma unroll
    for (int nt = 0; nt < 8; ++nt) {
        acc0[nt] = (f32x4){0.f, 0.f, 0.f, 0.f};
        acc1[nt] = (f32x4){0.f, 0.f, 0.f, 0.f};
    }
    const short* Xb = X + (size_t)b * NP * 256;
    const bf16x8 zv = {0, 0, 0, 0, 0, 0, 0, 0};
    for (int chunk = 0; chunk < 8; ++chunk) {
        int c0 = chunk * 32 + csub;
#pragma unroll
        for (int tap = 0; tap < 9; ++tap) {
            int dy = tap / 3 - 1, dx = tap % 3 - 1;
            int sy0 = py0 + dy, sx0 = px0 + dx;
            int sy1 = py1 + dy, sx1 = px1 + dx;
            bf16x8 a0 = zv, a1 = zv;
            if ((unsigned)sy0 < HW && (unsigned)sx0 < HW)
                a0 = *(const bf16x8*)(Xb + ((size_t)sy0 * HW + sx0) * 256 + c0);
            if ((unsigned)sy1 < HW && (unsigned)sx1 < HW)
                a1 = *(const bf16x8*)(Xb + ((size_t)sy1 * HW + sx1) * 256 + c0);
            const bf16x8* wbp = WB + (size_t)((chunk * 9 + tap) * 8) * 64 + lane;
#pragma unroll
            for (int nt = 0; nt < 8; ++nt) {
                bf16x8 bf = wbp[nt * 64];
                acc0[nt] = __builtin_amdgcn_mfma_f32_16x16x32_bf16(a0, bf, acc0[nt], 0, 0, 0);
                acc1[nt] = __builtin_amdgcn_mfma_f32_16x16x32_bf16(a1, bf, acc1[nt], 0, 0, 0);
            }
        }
    }
    int m0 = w * 32, m1 = w * 32 + 16;
#pragma unroll
    for (int nt = 0; nt < 8; ++nt) {
        int oc = nt * 16 + l15;
        float sh = shift[oc];
        float* ob = out + ((size_t)(b * 128 + oc)) * NP;
#pragma unroll
        for (int r = 0; r < 4; ++r) {
            int md = q * 4 + r;
            int lm = m0 + md;
            int py = ty0 + (lm >> 3), px = tx0 + (lm & 7);
            ob[py * HW + px] = fmaxf(acc0[nt][r] + sh, 0.f);
            lm = m1 + md;
            py = ty0 + (lm >> 3); px = tx0 + (lm & 7);
            ob[py * HW + px] = fmaxf(acc1[nt][r] + sh, 0.f);
        }
    }
}

// direct-load fp32 3x3 conv (conv2 / smooth)
template <int OCT, bool BN, bool RELU>
__global__ __launch_bounds__(256) void k_conv3(const float* __restrict__ in,
                                               const float* __restrict__ W,
                                               const float* __restrict__ bias,
                                               const float* __restrict__ bng,
                                               const float* __restrict__ bnb,
                                               const float* __restrict__ bnm,
                                               const float* __restrict__ bnv,
                                               float* __restrict__ out, int C, int O) {
    int tid = threadIdx.x;
    int tb = blockIdx.x;
    int ty = (tb / 7) * 32, tx = (tb % 7) * 32;
    int o0 = blockIdx.y * OCT;
    int b = blockIdx.z;
    int gx = tx + (tid & 15) * 2;
    int gy = ty + (tid >> 4) * 2;

    int roff[4], coff[4];
    float rmsk[4], cmsk[4];
#pragma unroll
    for (int i = 0; i < 4; ++i) {
        int sy = gy + i - 1;
        rmsk[i] = (sy >= 0 && sy < HW) ? 1.f : 0.f;
        roff[i] = min(max(sy, 0), HW - 1) * HW;
        int sx = gx + i - 1;
        cmsk[i] = (sx >= 0 && sx < HW) ? 1.f : 0.f;
        coff[i] = min(max(sx, 0), HW - 1);
    }
    float acc[OCT][4];
#pragma unroll
    for (int u = 0; u < OCT; ++u)
#pragma unroll
        for (int qq = 0; qq < 4; ++qq) acc[u][qq] = 0.f;

    const float* ic = in + (size_t)b * C * NP;
    const float* wbase = W + (size_t)o0 * C * 9;
    for (int c = 0; c < C; ++c) {
        float r[4][4];
#pragma unroll
        for (int i = 0; i < 4; ++i) {
            float m = rmsk[i];
#pragma unroll
            for (int j = 0; j < 4; ++j)
                r[i][j] = ic[roff[i] + coff[j]] * (m * cmsk[j]);
        }
        const float* wc = wbase + (size_t)c * 9;
#pragma unroll
        for (int u = 0; u < OCT; ++u) {
            const float* w = wc + (size_t)u * C * 9;
            float w0 = w[0], w1 = w[1], w2 = w[2];
            float w3 = w[3], w4 = w[4], w5 = w[5];
            float w6 = w[6], w7 = w[7], w8 = w[8];
            acc[u][0] = fmaf(r[0][0], w0, fmaf(r[0][1], w1, fmaf(r[0][2], w2,
                        fmaf(r[1][0], w3, fmaf(r[1][1], w4, fmaf(r[1][2], w5,
                        fmaf(r[2][0], w6, fmaf(r[2][1], w7, fmaf(r[2][2], w8, acc[u][0])))))))));
            acc[u][1] = fmaf(r[0][1], w0, fmaf(r[0][2], w1, fmaf(r[0][3], w2,
                        fmaf(r[1][1], w3, fmaf(r[1][2], w4, fmaf(r[1][3], w5,
                        fmaf(r[2][1], w6, fmaf(r[2][2], w7, fmaf(r[2][3], w8, acc[u][1])))))))));
            acc[u][2] = fmaf(r[1][0], w0, fmaf(r[1][1], w1, fmaf(r[1][2], w2,
                        fmaf(r[2][0], w3, fmaf(r[2][1], w4, fmaf(r[2][2], w5,
                        fmaf(r[3][0], w6, fmaf(r[3][1], w7, fmaf(r[3][2], w8, acc[u][2])))))))));
            acc[u][3] = fmaf(r[1][1], w0, fmaf(r[1][2], w1, fmaf(r[1][3], w2,
                        fmaf(r[2][1], w3, fmaf(r[2][2], w4, fmaf(r[2][3], w5,
                        fmaf(r[3][1], w6, fmaf(r[3][2], w7, fmaf(r[3][3], w8, acc[u][3])))))))));
        }
        ic += NP;
    }
    size_t obase = (size_t)b * O * NP + (size_t)gy * HW + gx;
#pragma unroll
    for (int u = 0; u < OCT; ++u) {
        int o = o0 + u;
        float bs = bias[o], sc = 1.f, sh = 0.f;
        if (BN) { sc = bng[o] * rsqrtf(bnv[o] + 1e-5f); sh = bnb[o] - bnm[o] * sc; }
        size_t ob = obase + (size_t)o * NP;
#pragma unroll
        for (int qq = 0; qq < 4; ++qq) {
            float v = acc[u][qq] + bs;
            if (BN) v = v * sc + sh;
            if (RELU) v = fmaxf(v, 0.f);
            out[ob + (qq >> 1) * HW + (qq & 1)] = v;
        }
    }
}

__global__ __launch_bounds__(256) void k_sim(const float* __restrict__ pe,
                                             const float* __restrict__ proto,
                                             float* __restrict__ sim) {
    int idx = blockIdx.x * 256 + threadIdx.x;
    int b = idx / NP, pos = idx - b * NP;
    const float* p = pe + (size_t)b * EMBD * NP + pos;
    float v[EMBD];
#pragma unroll
    for (int e = 0; e < EMBD; ++e) v[e] = p[(size_t)e * NP];
    const float scale = 1.0f / sqrtf(32.0f);
    float* so = sim + (size_t)b * NPROTO * NP + pos;
    for (int q = 0; q < NPROTO; ++q) {
        float acc = 0.f;
#pragma unroll
        for (int e = 0; e < EMBD; ++e) acc = fmaf(v[e], proto[q * EMBD + e], acc);
        so[(size_t)q * NP] = acc * scale;
    }
}

__global__ void k_init(float* acc) { if (threadIdx.x < 8) acc[threadIdx.x] = 0.f; }

__device__ __forceinline__ float block_reduce_sum(float v) {
    __shared__ float sh[4];
#pragma unroll
    for (int off = 32; off > 0; off >>= 1) v += __shfl_down(v, off);
    int lane = threadIdx.x & 63, wv = threadIdx.x >> 6;
    if (lane == 0) sh[wv] = v;
    __syncthreads();
    return (threadIdx.x == 0) ? (sh[0] + sh[1] + sh[2] + sh[3]) : 0.f;
}

__global__ __launch_bounds__(256) void k_edge(const float* __restrict__ pe,
                                              float* __restrict__ edge,
                                              float* __restrict__ acc) {
    int idx = blockIdx.x * 256 + threadIdx.x;
    int b = idx / NP, pos = idx - b * NP;
    int h = pos / HW, w = pos - h * HW;
    int wn = (w < HW - 1) ? w : HW - 2;
    int hn = (h < HW - 1) ? h : HW - 2;
    const float* pb = pe + (size_t)b * EMBD * NP;
    float sx = 0.f, sy = 0.f;
#pragma unroll 4
    for (int e = 0; e < EMBD; ++e) {
        const float* p = pb + (size_t)e * NP;
        sx += fabsf(p[h * HW + wn] - p[h * HW + wn + 1]);
        sy += fabsf(p[hn * HW + w] - p[hn * HW + HW + w]);
    }
    float ev = (sx + sy) * (0.5f / 32.0f);
    edge[idx] = ev;
    float tot = block_reduce_sum(ev);
    if (threadIdx.x == 0) atomicAdd(acc, tot);
}

__global__ void k_smooth(const float* __restrict__ sin_, const float* __restrict__ edge,
                         const float* __restrict__ acc, float* __restrict__ sout) {
    int idx = blockIdx.x * 256 + threadIdx.x;
    int pos = idx % NP;
    int bp = idx / NP;
    int b = bp >> 6;
    int h = pos / HW, w = pos - h * HW;
    float mean = acc[0] * (1.0f / 100352.0f);
    float m = (edge[(size_t)b * NP + pos] > mean) ? 1.f : 0.f;
    const float* sc = sin_ + (size_t)bp * NP;
    float s = 0.f;
#pragma unroll
    for (int dy = -1; dy <= 1; ++dy) {
        int yy = h + dy;
        if (yy < 0 || yy >= HW) continue;
#pragma unroll
        for (int dx = -1; dx <= 1; ++dx) {
            int xx = w + dx;
            if (xx < 0 || xx >= HW) continue;
            s += sc[yy * HW + xx];
        }
    }
    float c = sc[pos];
    sout[idx] = m * c + (1.f - m) * (s * (1.0f / 9.0f));
}

__global__ __launch_bounds__(256) void k_entropy(const float* __restrict__ sim,
                                                 float* __restrict__ acc) {
    int idx = blockIdx.x * 256 + threadIdx.x;
    int b = idx / NP, pos = idx - b * NP;
    const float* s = sim + (size_t)b * NPROTO * NP + pos;
    float v[NPROTO];
    float mx = -3.0e38f;
#pragma unroll
    for (int q = 0; q < NPROTO; ++q) { v[q] = s[(size_t)q * NP]; mx = fmaxf(mx, v[q]); }
    float sum = 0.f;
#pragma unroll
    for (int q = 0; q < NPROTO; ++q) { float e = expf(v[q] - mx); v[q] = e; sum += e; }
    float inv = 1.f / sum;
    float ent = 0.f;
#pragma unroll
    for (int q = 0; q < NPROTO; ++q) {
        float a = v[q] * inv;
        ent -= a * logf(a + 1e-8f);
    }
    float tot = block_reduce_sum(ent);
    if (threadIdx.x == 0) atomicAdd(acc + 1, tot);
}

__global__ void k_bb(const float* __restrict__ pb, const float* __restrict__ bs,
                     float* __restrict__ bbuf, float* __restrict__ obb) {
    int t = threadIdx.x;
    if (t < NPROTO) {
        float v = 1.f + tanhf(pb[t]) * bs[0];
        bbuf[t] = v;
        obb[t] = v;
        obb[NPROTO + t] = v;
    }
}

__global__ __launch_bounds__(256) void k_actsm(const float* __restrict__ sim,
                                               const float* __restrict__ bb,
                                               float* __restrict__ act,
                                               float* __restrict__ bgain) {
    int idx = blockIdx.x * 256 + threadIdx.x;
    int b = idx / NP, pos = idx - b * NP;
    const float* s = sim + (size_t)b * NPROTO * NP + pos;
    float v[NPROTO];
    float mx = -3.0e38f;
#pragma unroll
    for (int q = 0; q < NPROTO; ++q) { v[q] = s[(size_t)q * NP]; mx = fmaxf(mx, v[q]); }
    float sum = 0.f;
#pragma unroll
    for (int q = 0; q < NPROTO; ++q) { float e = expf(v[q] - mx); v[q] = e; sum += e; }
    float inv = 1.f / sum;
    float* a = act + (size_t)b * NPROTO * NP + pos;
    float bg = 0.f;
#pragma unroll
    for (int q = 0; q < NPROTO; ++q) {
        float p = v[q] * inv;
        a[(size_t)q * NP] = p;
        bg = fmaf(p, bb[q], bg);
    }
    bgain[idx] = bg;
}

__global__ void k_headprep(const float* __restrict__ w1, const float* __restrict__ b1,
                           const float* __restrict__ g1, const float* __restrict__ be1,
                           const float* __restrict__ m1, const float* __restrict__ v1,
                           const float* __restrict__ w2, const float* __restrict__ b2,
                           const float* __restrict__ g2, const float* __restrict__ be2,
                           const float* __restrict__ m2, const float* __restrict__ v2,
                           float* __restrict__ wf) {
    int oc = blockIdx.x * 256 + threadIdx.x;
    if (oc >= 512) return;
    float s1 = g1[oc] * rsqrtf(v1[oc] + 1e-5f);
#pragma unroll
    for (int k = 0; k < 9; ++k) wf[oc * 9 + k] = w1[oc * 9 + k] * s1;
    wf[41472 + oc] = (b1[oc] - m1[oc]) * s1 + be1[oc];
    float s2 = g2[oc] * rsqrtf(v2[oc] + 1e-5f);
    int g = oc >> 3, j = oc & 7;
#pragma unroll
    for (int icc = 0; icc < 8; ++icc)
#pragma unroll
        for (int k = 0; k < 9; ++k)
            wf[4608 + (size_t)g * 576 + icc * 72 + j * 9 + k] = w2[((size_t)oc * 8 + icc) * 9 + k] * s2;
    wf[41984 + oc] = (b2[oc] - m2[oc]) * s2 + be2[oc];
}

__global__ __launch_bounds__(256) void k_heads(
    const float* __restrict__ act, const float* __restrict__ wf,
    const float* __restrict__ w3, const float* __restrict__ b3,
    float* __restrict__ res) {
    __shared__ float sA[22 * 23];
    __shared__ float sH1[8][20 * 21];
    __shared__ float sH2[8][18 * 19];
    int tid = threadIdx.x;
    int tile = blockIdx.x, g = blockIdx.y, b = blockIdx.z;
    int oy0 = (tile / 14) * 16, ox0 = (tile % 14) * 16;
    const float* ain = act + (size_t)(b * NPROTO + g) * NP;

    for (int i = tid; i < 484; i += 256) {
        int y = i / 22, x = i - y * 22;
        int gy = oy0 - 3 + y, gx = ox0 - 3 + x;
        float v = 0.f;
        if ((unsigned)gy < HW && (unsigned)gx < HW) v = ain[gy * HW + gx];
        sA[y * 23 + x] = v;
    }
    __syncthreads();

    const float* b1f = wf + 41472 + g * 8;
    for (int i = tid; i < 400; i += 256) {
        int y = i / 20, x = i - y * 20;
        int gy = oy0 - 2 + y, gx = ox0 - 2 + x;
        float keep = ((unsigned)gy < HW && (unsigned)gx < HW) ? 1.f : 0.f;
        const float* s0 = sA + y * 23 + x;
        float r0 = s0[0],  r1 = s0[1],  r2 = s0[2];
        float r3 = s0[23], r4 = s0[24], r5 = s0[25];
        float r6 = s0[46], r7 = s0[47], r8 = s0[48];
#pragma unroll
        for (int j = 0; j < 8; ++j) {
            const float* w = wf + (g * 8 + j) * 9;
            float v = fmaf(r0, w[0], fmaf(r1, w[1], fmaf(r2, w[2],
                      fmaf(r3, w[3], fmaf(r4, w[4], fmaf(r5, w[5],
                      fmaf(r6, w[6], fmaf(r7, w[7], fmaf(r8, w[8], b1f[j])))))))));
            sH1[j][y * 21 + x] = fmaxf(v, 0.f) * keep;
        }
    }
    __syncthreads();

    const float* w2f = wf + 4608 + (size_t)g * 576;
    const float* b2f = wf + 41984 + g * 8;
    for (int i = tid; i < 324; i += 256) {
        int y = i / 18, x = i - y * 18;
        int gy = oy0 - 1 + y, gx = ox0 - 1 + x;
        float keep = ((unsigned)gy < HW && (unsigned)gx < HW) ? 1.f : 0.f;
        float a[8];
#pragma unroll
        for (int j = 0; j < 8; ++j) a[j] = b2f[j];
#pragma unroll
        for (int icc = 0; icc < 8; ++icc) {
            const float* s0 = &sH1[icc][y * 21 + x];
            float r0 = s0[0],  r1 = s0[1],  r2 = s0[2];
            float r3 = s0[21], r4 = s0[22], r5 = s0[23];
            float r6 = s0[42], r7 = s0[43], r8 = s0[44];
            const float* w = w2f + icc * 72;
#pragma unroll
            for (int j = 0; j < 8; ++j) {
                const float* wj = w + j * 9;
                a[j] = fmaf(r0, wj[0], fmaf(r1, wj[1], fmaf(r2, wj[2],
                       fmaf(r3, wj[3], fmaf(r4, wj[4], fmaf(r5, wj[5],
                       fmaf(r6, wj[6], fmaf(r7, wj[7], fmaf(r8, wj[8], a[j])))))))));
            }
        }
#pragma unroll
        for (int j = 0; j < 8; ++j)
            sH2[j][y * 19 + x] = fmaxf(a[j], 0.f) * keep;
    }
    __syncthreads();

    {
        int y = tid >> 4, x = tid & 15;
        float accv = b3[g];
#pragma unroll
        for (int icc = 0; icc < 8; ++icc) {
            const float* s0 = &sH2[icc][y * 19 + x];
            const float* w = w3 + (size_t)(g * 8 + icc) * 9;
            accv = fmaf(s0[0],  w[0], fmaf(s0[1],  w[1], fmaf(s0[2],  w[2],
                   fmaf(s0[19], w[3], fmaf(s0[20], w[4], fmaf(s0[21], w[5],
                   fmaf(s0[38], w[6], fmaf(s0[39], w[7], fmaf(s0[40], w[8], accv)))))))));
        }
        res[(size_t)(b * NPROTO + g) * NP + (size_t)(oy0 + y) * HW + (ox0 + x)] = accv;
    }
}

__global__ __launch_bounds__(256) void k_final(const float* __restrict__ act,
                                               const float* __restrict__ res,
                                               const float* __restrict__ bgain,
                                               const float* __restrict__ rscale,
                                               float* __restrict__ owt,
                                               float* __restrict__ oibm) {
    int idx = blockIdx.x * 256 + threadIdx.x;
    int b = idx / NP, pos = idx - b * NP;
    const float* a = act + (size_t)b * NPROTO * NP + pos;
    const float* r = res + (size_t)b * NPROTO * NP + pos;
    float wt = 0.f;
#pragma unroll
    for (int q = 0; q < NPROTO; ++q) wt = fmaf(a[(size_t)q * NP], r[(size_t)q * NP], wt);
    owt[idx] = wt;
    float gn = bgain[idx] * (1.f + tanhf(wt) * rscale[0]);
    gn = fminf(fmaxf(gn, 0.5f), 2.0f);
    oibm[idx] = gn;
}

__global__ void k_entfinal(const float* __restrict__ acc, float* __restrict__ o) {
    if (threadIdx.x == 0) o[0] = acc[1] * (1.0f / 100352.0f);
}

// ======================================================================
extern "C" void kernel_launch(void* const* d_in, const int* in_sizes, int n_in,
                              void* d_out, int out_size, void* d_ws, size_t ws_size,
                              hipStream_t stream) {
    const float* tokens[4] = {(const float*)d_in[0], (const float*)d_in[1],
                              (const float*)d_in[2], (const float*)d_in[3]};
    const float* proj_w[4] = {(const float*)d_in[4], (const float*)d_in[6],
                              (const float*)d_in[8], (const float*)d_in[10]};
    const float* proj_b[4] = {(const float*)d_in[5], (const float*)d_in[7],
                              (const float*)d_in[9], (const float*)d_in[11]};
    const float* up_w0 = (const float*)d_in[12]; const float* up_b0 = (const float*)d_in[13];
    const float* up_w1 = (const float*)d_in[14]; const float* up_b1 = (const float*)d_in[15];
    const float* down_w3 = (const float*)d_in[16]; const float* down_b3 = (const float*)d_in[17];
    const float* fuse_w = (const float*)d_in[18]; const float* fuse_b = (const float*)d_in[19];
    const float* pe_w1 = (const float*)d_in[20]; const float* pe_b1 = (const float*)d_in[21];
    const float* pe_bn_g = (const float*)d_in[22]; const float* pe_bn_b = (const float*)d_in[23];
    const float* pe_bn_m = (const float*)d_in[24]; const float* pe_bn_v = (const float*)d_in[25];
    const float* pe_w2 = (const float*)d_in[26]; const float* pe_b2 = (const float*)d_in[27];
    const float* prototypes = (const float*)d_in[28];
    const float* proto_biases = (const float*)d_in[29];
    const float* bias_scale = (const float*)d_in[30];
    const float* smooth_w = (const float*)d_in[31]; const float* smooth_b = (const float*)d_in[32];
    const float* hw1 = (const float*)d_in[33]; const float* hb1 = (const float*)d_in[34];
    const float* hg1 = (const float*)d_in[35]; const float* hbe1 = (const float*)d_in[36];
    const float* hm1 = (const float*)d_in[37]; const float* hv1 = (const float*)d_in[38];
    const float* hw2 = (const float*)d_in[39]; const float* hb2 = (const float*)d_in[40];
    const float* hg2 = (const float*)d_in[41]; const float* hbe2 = (const float*)d_in[42];
    const float* hm2 = (const float*)d_in[43]; const float* hv2 = (const float*)d_in[44];
    const float* hw3 = (const float*)d_in[45]; const float* hb3 = (const float*)d_in[46];
    const float* rscale = (const float*)d_in[47];
    (void)in_sizes; (void)n_in; (void)out_size; (void)ws_size;

    float* ws = (float*)d_ws;
    float* FEATS[4] = {ws + OFF_FEATS0, ws + OFF_FEATS1, ws + OFF_FEATS2, ws + OFF_FEATS3};
    float* TOKT = ws + OFF_TOKT;
    float* F0 = ws + OFF_F0; float* F1 = ws + OFF_F1; float* F3 = ws + OFF_F3;
    float* FUSED = ws + OFF_FUSED;
    float* PATH64 = ws + OFF_PATH64;
    short* P224C = (short*)(ws + OFF_P224C);
    short* WB = (short*)(ws + OFF_WB);
    float* SHIFT = ws + OFF_SHIFT;
    float* T1 = ws + OFF_T1;
    float* SIMA = ws + OFF_SIMA; float* SIMB = ws + OFF_SIMB;
    float* EDGE = ws + OFF_EDGE; float* RES = ws + OFF_RES;
    float* BGAIN = ws + OFF_BGAIN; float* BBUF = ws + OFF_BB; float* ACC = ws + OFF_ACC;
    float* WF = ws + OFF_WF;

    float* out = (float*)d_out;
    float* o_ibm = out + O_IBM; float* o_act = out + O_ACT; float* o_bb = out + O_BB;
    float* o_wt = out + O_WT; float* o_pe = out + O_PE; float* o_ent = out + O_ENT;

    const int OCH[4] = {256, 512, 1024, 1024};
    for (int s = 0; s < 4; ++s)
        k_transpose<<<768, 256, 0, stream>>>(tokens[s], TOKT + s * 196608);
    for (int s = 0; s < 4; ++s)
        k_proj<<<dim3(OCH[s], BATCH), 256, 0, stream>>>(TOKT + s * 196608, proj_w[s], proj_b[s],
                                                        FEATS[s], OCH[s]);
    k_convt<<<dim3(16, 256, BATCH), 256, 0, stream>>>(FEATS[0], up_w0, up_b0, F0, 256, 256, 4);
    k_convt<<<dim3(4, 512, BATCH), 256, 0, stream>>>(FEATS[1], up_w1, up_b1, F1, 512, 512, 2);
    k_down<<<dim3(1024, BATCH), 256, 0, stream>>>(FEATS[3], down_w3, down_b3, F3);
    k_fusedcat<<<90112, 256, 0, stream>>>(F0, F1, FEATS[2], F3, FUSED);
    k_fuse<16><<<dim3(16, 16, BATCH), 256, 0, stream>>>(FUSED, fuse_w, fuse_b, PATH64);
    // FUSED now dead: WB/P224C regions safe to write
    k_w1prep<<<1152, 256, 0, stream>>>(pe_w1, pe_b1, pe_bn_g, pe_bn_b, pe_bn_m, pe_bn_v,
                                       WB, SHIFT);
    k_resize224bf<<<100352, 256, 0, stream>>>(PATH64, P224C);
    k_conv1mfma<<<dim3(392, BATCH), 256, 0, stream>>>(P224C, (const bf16x8*)WB, SHIFT, T1);
    k_conv3<4, false, false><<<dim3(49, 8, BATCH), 256, 0, stream>>>(
        T1, pe_w2, pe_b2, nullptr, nullptr, nullptr, nullptr, o_pe, 128, 32);
    k_sim<<<392, 256, 0, stream>>>(o_pe, prototypes, SIMA);
    k_init<<<1, 64, 0, stream>>>(ACC);
    k_edge<<<392, 256, 0, stream>>>(o_pe, EDGE, ACC);
    k_smooth<<<25088, 256, 0, stream>>>(SIMA, EDGE, ACC, SIMB);
    k_smooth<<<25088, 256, 0, stream>>>(SIMB, EDGE, ACC, SIMA);
    k_entropy<<<392, 256, 0, stream>>>(SIMA, ACC);
    k_conv3<8, false, false><<<dim3(49, 8, BATCH), 256, 0, stream>>>(
        SIMA, smooth_w, smooth_b, nullptr, nullptr, nullptr, nullptr, SIMB, 64, 64);
    k_bb<<<1, 64, 0, stream>>>(proto_biases, bias_scale, BBUF, o_bb);
    k_actsm<<<392, 256, 0, stream>>>(SIMB, BBUF, o_act, BGAIN);
    k_headprep<<<2, 256, 0, stream>>>(hw1, hb1, hg1, hbe1, hm1, hv1,
                                      hw2, hb2, hg2, hbe2, hm2, hv2, WF);
    k_heads<<<dim3(196, 64, BATCH), 256, 0, stream>>>(o_act, WF, hw3, hb3, RES);
    k_final<<<392, 256, 0, stream>>>(o_act, RES, BGAIN, rscale, o_wt, o_ibm);
    k_entfinal<<<1, 1, 0, stream>>>(ACC, o_ent);
}

// Round 10
// 2574.219 us; speedup vs baseline: 1.7610x; 1.2892x over previous
//
#include <hip/hip_runtime.h>
#include <math.h>

// ---------------- problem constants ----------------
#define BATCH 2
#define NTOK 256
#define INCH 384
#define NP 50176          // 224*224
#define HW 224
#define NPROTO 64
#define EMBD 32

// ---------------- workspace layout (floats) ----------------
#define OFF_FEATS0   0u
#define OFF_FEATS1   131072u
#define OFF_FEATS2   393216u
#define OFF_FEATS3   917504u
#define OFF_TOKT     1441792u
#define OFF_F0       2228224u
#define OFF_F1       4325376u
#define OFF_F3       5373952u
#define OFF_FUSEDBF  5505024u      // (2,4096,2816) bf16 = 11.53M fl -> ends 17.04M
#define OFF_P64C     28573696u     // (2,4096,256) bf16 channels-last
#define OFF_P224C    0u            // (2,224,224,256) bf16 = 12.85M fl
#define OFF_T1       25690112u     // (2,128,224,224) fp32
#define OFF_SIMA     0u
#define OFF_SIMB     6422528u
#define OFF_EDGE     12845056u
#define OFF_RES      13000000u
#define OFF_WB       13000000u     // conv1 MFMA weight frags (dead-RES window, written after fuse)
#define OFF_SHIFT    13200000u
#define OFF_BGAIN    19422528u
#define OFF_BB       19522880u
#define OFF_ACC      19523008u
#define OFF_WF       19523072u     // folded head weights (42496 fl)
#define OFF_WFUSE    20000000u     // fuse MFMA weight frags: 720896 bf16 = 360448 fl

// ---------------- output layout ----------------
#define O_IBM 0u
#define O_ACT 100352u
#define O_BB  6522880u
#define O_WT  6523008u
#define O_PE  6623360u
#define O_ENT 9834624u

typedef __attribute__((ext_vector_type(8))) short bf16x8;
typedef __attribute__((ext_vector_type(4))) float f32x4;
typedef __attribute__((ext_vector_type(2))) float f32x2;

__device__ __forceinline__ short f2bf(float f) {
    unsigned u = __float_as_uint(f);
    unsigned r = (u + 0x7fffu + ((u >> 16) & 1u)) >> 16;
    return (short)r;
}
__device__ __forceinline__ float bf2f(short s) {
    return __uint_as_float(((unsigned)(unsigned short)s) << 16);
}

// ======================================================================
__global__ void k_transpose(const float* __restrict__ in, float* __restrict__ out) {
    int idx = blockIdx.x * 256 + threadIdx.x;
    int n = idx & 255;
    int c = (idx >> 8) % INCH;
    int b = idx / (INCH * NTOK);
    out[idx] = in[(size_t)b * INCH * NTOK + (size_t)n * INCH + c];
}

__global__ __launch_bounds__(256) void k_proj(const float* __restrict__ A,
                                              const float* __restrict__ W,
                                              const float* __restrict__ bias,
                                              float* __restrict__ out, int O) {
    int p = threadIdx.x;
    int o = blockIdx.x, b = blockIdx.y;
    const float* a = A + (size_t)b * INCH * NTOK + p;
    const float* w = W + (size_t)o * INCH;
    float acc = bias[o];
    for (int c = 0; c < INCH; ++c) acc = fmaf(a[(size_t)c * NTOK], w[c], acc);
    out[((size_t)b * O + o) * NTOK + p] = acc;
}

__global__ void k_convt(const float* __restrict__ X, const float* __restrict__ W,
                        const float* __restrict__ bias, float* __restrict__ out,
                        int C, int O, int K) {
    int S = 16 * K;
    int p = blockIdx.x * 256 + threadIdx.x;
    int o = blockIdx.y, b = blockIdx.z;
    int yy = p / S, xx = p - yy * S;
    int h = yy / K, i = yy - h * K, w = xx / K, j = xx - w * K;
    const float* Xb = X + (size_t)b * C * 256 + h * 16 + w;
    const float* Wb = W + ((size_t)o * K + i) * K + j;
    size_t wstride = (size_t)O * K * K;
    float acc = bias[o];
    for (int c = 0; c < C; ++c) acc = fmaf(Xb[(size_t)c * 256], Wb[(size_t)c * wstride], acc);
    out[((size_t)b * O + o) * (size_t)(S * S) + p] = acc;
}

// 3x3 stride2 pad1 with LDS-staged weights (R9 version — kept)
__global__ __launch_bounds__(256) void k_down(const float* __restrict__ X,
                                              const float* __restrict__ W,
                                              const float* __restrict__ bias,
                                              float* __restrict__ out) {
    __shared__ float wsh[9216];
    __shared__ float red[3][64];
    int tid = threadIdx.x;
    int o = blockIdx.x, b = blockIdx.y;
    const float* Wo = W + (size_t)o * 9216;
    for (int i = tid; i < 9216; i += 256) wsh[i] = Wo[i];
    __syncthreads();
    int p = tid & 63, s = tid >> 6;
    int oh = p >> 3, ow = p & 7;
    int ro[3], co[3];
    float rm[3], cm[3];
#pragma unroll
    for (int i = 0; i < 3; ++i) {
        int sy = oh * 2 + i - 1;
        rm[i] = (sy >= 0) ? 1.f : 0.f;
        ro[i] = (sy > 0 ? sy : 0) * 16;
        int sx = ow * 2 + i - 1;
        cm[i] = (sx >= 0) ? 1.f : 0.f;
        co[i] = (sx > 0 ? sx : 0);
    }
    float msk[9];
#pragma unroll
    for (int i = 0; i < 3; ++i)
#pragma unroll
        for (int j = 0; j < 3; ++j) msk[i * 3 + j] = rm[i] * cm[j];
    const float* Xb = X + ((size_t)b * 1024 + s * 256) * 256;
    const float* wb = wsh + s * 256 * 9;
    float acc0 = 0.f, acc1 = 0.f;
    for (int c = 0; c < 256; c += 2) {
        const float* xc0 = Xb + c * 256;
        const float* xc1 = xc0 + 256;
        const float* wc0 = wb + c * 9;
        const float* wc1 = wc0 + 9;
        float t0[9], t1[9];
#pragma unroll
        for (int i = 0; i < 3; ++i)
#pragma unroll
            for (int j = 0; j < 3; ++j) {
                int k = i * 3 + j, a = ro[i] + co[j];
                t0[k] = xc0[a] * msk[k];
                t1[k] = xc1[a] * msk[k];
            }
#pragma unroll
        for (int k = 0; k < 9; ++k) {
            acc0 = fmaf(t0[k], wc0[k], acc0);
            acc1 = fmaf(t1[k], wc1[k], acc1);
        }
    }
    float acc = acc0 + acc1;
    if (s) red[s - 1][p] = acc;
    __syncthreads();
    if (s == 0) {
        acc += red[0][p] + red[1][p] + red[2][p];
        out[((size_t)b * 1024 + o) * 64 + p] = acc + bias[o];
    }
}

// fused concat -> bf16 CHANNELS-LAST (b, pos4096, ch2816)
__global__ void k_fusedcat_bf(const float* __restrict__ f0, const float* __restrict__ f1,
                              const float* __restrict__ f2, const float* __restrict__ f3,
                              short* __restrict__ out) {
    int idx = blockIdx.x * 256 + threadIdx.x;       // < 23068672
    int ch = idx % 2816;
    int t = idx / 2816;
    int pos = t & 4095;
    int b = t >> 12;
    float v;
    if (ch < 256) {
        v = f0[((size_t)(b * 256 + ch)) * 4096 + pos];
    } else {
        const float* src; int sh;
        if (ch < 768)       { src = f1 + ((size_t)(b * 512 + (ch - 256))) * 1024; sh = 32; }
        else if (ch < 1792) { src = f2 + ((size_t)(b * 1024 + (ch - 768))) * 256; sh = 16; }
        else                { src = f3 + ((size_t)(b * 1024 + (ch - 1792))) * 64; sh = 8;  }
        int y = pos >> 6, x = pos & 63;
        float r = (float)(sh - 1) / 63.0f;
        float cy = y * r, cx = x * r;
        int i0 = (int)cy; if (i0 > sh - 2) i0 = sh - 2;
        int j0 = (int)cx; if (j0 > sh - 2) j0 = sh - 2;
        float ty = cy - (float)i0, tx = cx - (float)j0;
        const float* s0 = src + i0 * sh + j0;
        float v00 = s0[0], v01 = s0[1], v10 = s0[sh], v11 = s0[sh + 1];
        float c0 = v00 + ty * (v10 - v00);
        float c1 = v01 + ty * (v11 - v01);
        v = c0 + tx * (c1 - c0);
    }
    out[idx] = f2bf(v);
}

// fuse weight prep: bf16 B-fragment order for 16x16x32 MFMA.
// wb[((chunk*16+ntile)*64+lane)*8+j] = W[oc=ntile*16+(lane&15)][c=chunk*32+(lane>>4)*8+j]
__global__ void k_wfuseprep(const float* __restrict__ w, short* __restrict__ wb) {
    int idx = blockIdx.x * 256 + threadIdx.x;       // < 720896
    int j = idx & 7;
    int lane = (idx >> 3) & 63;
    int ntile = (idx >> 9) & 15;
    int chunk = idx >> 13;                          // < 88
    int oc = ntile * 16 + (lane & 15);
    int c = chunk * 32 + (lane >> 4) * 8 + j;
    wb[idx] = f2bf(w[(size_t)oc * 2816 + c]);
}

// fuse GEMM on MFMA bf16: M=8192 px, N=256 oc, K=2816.
// block = 16 px x 256 oc; 4 waves each take 64 oc (4 n-tiles).
__global__ __launch_bounds__(256) void k_fuse_mfma(const short* __restrict__ A,
                                                   const bf16x8* __restrict__ WB,
                                                   const float* __restrict__ bias,
                                                   short* __restrict__ out) {
    int tid = threadIdx.x;
    int lane = tid & 63, w = tid >> 6;
    int row0 = blockIdx.x * 16;                     // global px row of tile
    int l15 = lane & 15, q = lane >> 4;
    int arow = row0 + l15;
    f32x4 acc[4];
#pragma unroll
    for (int nn = 0; nn < 4; ++nn) acc[nn] = (f32x4){0.f, 0.f, 0.f, 0.f};
    const short* arp = A + (size_t)arow * 2816 + q * 8;
    for (int chunk = 0; chunk < 88; ++chunk) {
        bf16x8 a = *(const bf16x8*)(arp + chunk * 32);
        const bf16x8* wbp = WB + ((size_t)(chunk * 16 + w * 4) * 64) + lane;
#pragma unroll
        for (int nn = 0; nn < 4; ++nn) {
            bf16x8 bf = wbp[nn * 64];
            acc[nn] = __builtin_amdgcn_mfma_f32_16x16x32_bf16(a, bf, acc[nn], 0, 0, 0);
        }
    }
#pragma unroll
    for (int nn = 0; nn < 4; ++nn) {
        int oc = (w * 4 + nn) * 16 + l15;
        float bs = bias[oc];
#pragma unroll
        for (int r = 0; r < 4; ++r) {
            int m = q * 4 + r;
            out[(size_t)(row0 + m) * 256 + oc] = f2bf(fmaxf(acc[nn][r] + bs, 0.f));
        }
    }
}

// bilinear 64->224 on bf16 channels-last, 8 ch per thread
__global__ void k_resize224bf2(const short* __restrict__ in, short* __restrict__ out) {
    int idx = blockIdx.x * 256 + threadIdx.x;       // < 3211264
    int c8 = (idx & 31) * 8;
    int p = idx >> 5;                               // < 100352
    int b = p / NP;
    int pos = p - b * NP;
    int y = pos / HW, x = pos - y * HW;
    const float r = (float)(63.0 / 223.0);
    float cy = y * r, cx = x * r;
    int i0 = (int)cy; if (i0 > 62) i0 = 62;
    int j0 = (int)cx; if (j0 > 62) j0 = 62;
    float ty = cy - (float)i0, tx = cx - (float)j0;
    const short* base = in + ((size_t)b * 4096) * 256 + c8;
    const bf16x8 v00 = *(const bf16x8*)(base + (size_t)(i0 * 64 + j0) * 256);
    const bf16x8 v01 = *(const bf16x8*)(base + (size_t)(i0 * 64 + j0 + 1) * 256);
    const bf16x8 v10 = *(const bf16x8*)(base + (size_t)((i0 + 1) * 64 + j0) * 256);
    const bf16x8 v11 = *(const bf16x8*)(base + (size_t)((i0 + 1) * 64 + j0 + 1) * 256);
    bf16x8 o;
#pragma unroll
    for (int k = 0; k < 8; ++k) {
        float a00 = bf2f(v00[k]), a01 = bf2f(v01[k]);
        float a10 = bf2f(v10[k]), a11 = bf2f(v11[k]);
        float c0 = a00 + ty * (a10 - a00);
        float c1 = a01 + ty * (a11 - a01);
        o[k] = f2bf(c0 + tx * (c1 - c0));
    }
    *(bf16x8*)(out + ((size_t)b * NP + pos) * 256 + c8) = o;
}

// conv1 weight prep: BN-fold + bf16 + MFMA B-fragment order.
__global__ void k_w1prep(const float* __restrict__ w, const float* __restrict__ bias,
                         const float* __restrict__ g, const float* __restrict__ bb,
                         const float* __restrict__ m, const float* __restrict__ v,
                         short* __restrict__ wb, float* __restrict__ shift) {
    int idx = blockIdx.x * 256 + threadIdx.x;      // < 294912
    int j = idx & 7;
    int lane = (idx >> 3) & 63;
    int nt = (idx >> 9) & 7;
    int tc = idx >> 12;
    int tap = tc % 9, chunk = tc / 9;
    int oc = nt * 16 + (lane & 15);
    int c = chunk * 32 + (lane >> 4) * 8 + j;
    float s = g[oc] * rsqrtf(v[oc] + 1e-5f);
    wb[idx] = f2bf(w[((size_t)oc * 256 + c) * 9 + tap] * s);
    if (idx < 128) {
        float si = g[idx] * rsqrtf(v[idx] + 1e-5f);
        shift[idx] = (bias[idx] - m[idx]) * si + bb[idx];
    }
}

// conv1 as implicit GEMM on MFMA bf16.
__global__ __launch_bounds__(256) void k_conv1mfma(const short* __restrict__ X,
                                                   const bf16x8* __restrict__ WB,
                                                   const float* __restrict__ shift,
                                                   float* __restrict__ out) {
    int tid = threadIdx.x;
    int lane = tid & 63, w = tid >> 6;
    int t = blockIdx.x;
    int b = blockIdx.y;
    int ty0 = (t / 28) * 16, tx0 = (t % 28) * 8;
    int l15 = lane & 15, q = lane >> 4;
    int loc0 = w * 32 + l15;
    int loc1 = loc0 + 16;
    int py0 = ty0 + (loc0 >> 3), px0 = tx0 + (loc0 & 7);
    int py1 = ty0 + (loc1 >> 3), px1 = tx0 + (loc1 & 7);
    int csub = q * 8;
    f32x4 acc0[8], acc1[8];
#pragma unroll
    for (int nt = 0; nt < 8; ++nt) {
        acc0[nt] = (f32x4){0.f, 0.f, 0.f, 0.f};
        acc1[nt] = (f32x4){0.f, 0.f, 0.f, 0.f};
    }
    const short* Xb = X + (size_t)b * NP * 256;
    const bf16x8 zv = {0, 0, 0, 0, 0, 0, 0, 0};
    for (int chunk = 0; chunk < 8; ++chunk) {
        int c0 = chunk * 32 + csub;
#pragma unroll
        for (int tap = 0; tap < 9; ++tap) {
            int dy = tap / 3 - 1, dx = tap % 3 - 1;
            int sy0 = py0 + dy, sx0 = px0 + dx;
            int sy1 = py1 + dy, sx1 = px1 + dx;
            bf16x8 a0 = zv, a1 = zv;
            if ((unsigned)sy0 < HW && (unsigned)sx0 < HW)
                a0 = *(const bf16x8*)(Xb + ((size_t)sy0 * HW + sx0) * 256 + c0);
            if ((unsigned)sy1 < HW && (unsigned)sx1 < HW)
                a1 = *(const bf16x8*)(Xb + ((size_t)sy1 * HW + sx1) * 256 + c0);
            const bf16x8* wbp = WB + (size_t)((chunk * 9 + tap) * 8) * 64 + lane;
#pragma unroll
            for (int nt = 0; nt < 8; ++nt) {
                bf16x8 bf = wbp[nt * 64];
                acc0[nt] = __builtin_amdgcn_mfma_f32_16x16x32_bf16(a0, bf, acc0[nt], 0, 0, 0);
                acc1[nt] = __builtin_amdgcn_mfma_f32_16x16x32_bf16(a1, bf, acc1[nt], 0, 0, 0);
            }
        }
    }
    int m0 = w * 32, m1 = w * 32 + 16;
#pragma unroll
    for (int nt = 0; nt < 8; ++nt) {
        int oc = nt * 16 + l15;
        float sh = shift[oc];
        float* ob = out + ((size_t)(b * 128 + oc)) * NP;
#pragma unroll
        for (int r = 0; r < 4; ++r) {
            int md = q * 4 + r;
            int lm = m0 + md;
            int py = ty0 + (lm >> 3), px = tx0 + (lm & 7);
            ob[py * HW + px] = fmaxf(acc0[nt][r] + sh, 0.f);
            lm = m1 + md;
            py = ty0 + (lm >> 3); px = tx0 + (lm & 7);
            ob[py * HW + px] = fmaxf(acc1[nt][r] + sh, 0.f);
        }
    }
}

// direct-load fp32 3x3 conv (conv2 / smooth)
template <int OCT, bool BN, bool RELU>
__global__ __launch_bounds__(256) void k_conv3(const float* __restrict__ in,
                                               const float* __restrict__ W,
                                               const float* __restrict__ bias,
                                               const float* __restrict__ bng,
                                               const float* __restrict__ bnb,
                                               const float* __restrict__ bnm,
                                               const float* __restrict__ bnv,
                                               float* __restrict__ out, int C, int O) {
    int tid = threadIdx.x;
    int tb = blockIdx.x;
    int ty = (tb / 7) * 32, tx = (tb % 7) * 32;
    int o0 = blockIdx.y * OCT;
    int b = blockIdx.z;
    int gx = tx + (tid & 15) * 2;
    int gy = ty + (tid >> 4) * 2;

    int roff[4], coff[4];
    float rmsk[4], cmsk[4];
#pragma unroll
    for (int i = 0; i < 4; ++i) {
        int sy = gy + i - 1;
        rmsk[i] = (sy >= 0 && sy < HW) ? 1.f : 0.f;
        roff[i] = min(max(sy, 0), HW - 1) * HW;
        int sx = gx + i - 1;
        cmsk[i] = (sx >= 0 && sx < HW) ? 1.f : 0.f;
        coff[i] = min(max(sx, 0), HW - 1);
    }
    float acc[OCT][4];
#pragma unroll
    for (int u = 0; u < OCT; ++u)
#pragma unroll
        for (int qq = 0; qq < 4; ++qq) acc[u][qq] = 0.f;

    const float* ic = in + (size_t)b * C * NP;
    const float* wbase = W + (size_t)o0 * C * 9;
    for (int c = 0; c < C; ++c) {
        float r[4][4];
#pragma unroll
        for (int i = 0; i < 4; ++i) {
            float m = rmsk[i];
#pragma unroll
            for (int j = 0; j < 4; ++j)
                r[i][j] = ic[roff[i] + coff[j]] * (m * cmsk[j]);
        }
        const float* wc = wbase + (size_t)c * 9;
#pragma unroll
        for (int u = 0; u < OCT; ++u) {
            const float* w = wc + (size_t)u * C * 9;
            float w0 = w[0], w1 = w[1], w2 = w[2];
            float w3 = w[3], w4 = w[4], w5 = w[5];
            float w6 = w[6], w7 = w[7], w8 = w[8];
            acc[u][0] = fmaf(r[0][0], w0, fmaf(r[0][1], w1, fmaf(r[0][2], w2,
                        fmaf(r[1][0], w3, fmaf(r[1][1], w4, fmaf(r[1][2], w5,
                        fmaf(r[2][0], w6, fmaf(r[2][1], w7, fmaf(r[2][2], w8, acc[u][0])))))))));
            acc[u][1] = fmaf(r[0][1], w0, fmaf(r[0][2], w1, fmaf(r[0][3], w2,
                        fmaf(r[1][1], w3, fmaf(r[1][2], w4, fmaf(r[1][3], w5,
                        fmaf(r[2][1], w6, fmaf(r[2][2], w7, fmaf(r[2][3], w8, acc[u][1])))))))));
            acc[u][2] = fmaf(r[1][0], w0, fmaf(r[1][1], w1, fmaf(r[1][2], w2,
                        fmaf(r[2][0], w3, fmaf(r[2][1], w4, fmaf(r[2][2], w5,
                        fmaf(r[3][0], w6, fmaf(r[3][1], w7, fmaf(r[3][2], w8, acc[u][2])))))))));
            acc[u][3] = fmaf(r[1][1], w0, fmaf(r[1][2], w1, fmaf(r[1][3], w2,
                        fmaf(r[2][1], w3, fmaf(r[2][2], w4, fmaf(r[2][3], w5,
                        fmaf(r[3][1], w6, fmaf(r[3][2], w7, fmaf(r[3][3], w8, acc[u][3])))))))));
        }
        ic += NP;
    }
    size_t obase = (size_t)b * O * NP + (size_t)gy * HW + gx;
#pragma unroll
    for (int u = 0; u < OCT; ++u) {
        int o = o0 + u;
        float bs = bias[o], sc = 1.f, sh = 0.f;
        if (BN) { sc = bng[o] * rsqrtf(bnv[o] + 1e-5f); sh = bnb[o] - bnm[o] * sc; }
        size_t ob = obase + (size_t)o * NP;
#pragma unroll
        for (int qq = 0; qq < 4; ++qq) {
            float v = acc[u][qq] + bs;
            if (BN) v = v * sc + sh;
            if (RELU) v = fmaxf(v, 0.f);
            out[ob + (qq >> 1) * HW + (qq & 1)] = v;
        }
    }
}

__global__ __launch_bounds__(256) void k_sim(const float* __restrict__ pe,
                                             const float* __restrict__ proto,
                                             float* __restrict__ sim) {
    int idx = blockIdx.x * 256 + threadIdx.x;
    int b = idx / NP, pos = idx - b * NP;
    const float* p = pe + (size_t)b * EMBD * NP + pos;
    float v[EMBD];
#pragma unroll
    for (int e = 0; e < EMBD; ++e) v[e] = p[(size_t)e * NP];
    const float scale = 1.0f / sqrtf(32.0f);
    float* so = sim + (size_t)b * NPROTO * NP + pos;
    for (int q = 0; q < NPROTO; ++q) {
        float acc = 0.f;
#pragma unroll
        for (int e = 0; e < EMBD; ++e) acc = fmaf(v[e], proto[q * EMBD + e], acc);
        so[(size_t)q * NP] = acc * scale;
    }
}

__global__ void k_init(float* acc) { if (threadIdx.x < 8) acc[threadIdx.x] = 0.f; }

__device__ __forceinline__ float block_reduce_sum(float v) {
    __shared__ float sh[4];
#pragma unroll
    for (int off = 32; off > 0; off >>= 1) v += __shfl_down(v, off);
    int lane = threadIdx.x & 63, wv = threadIdx.x >> 6;
    if (lane == 0) sh[wv] = v;
    __syncthreads();
    return (threadIdx.x == 0) ? (sh[0] + sh[1] + sh[2] + sh[3]) : 0.f;
}

__global__ __launch_bounds__(256) void k_edge(const float* __restrict__ pe,
                                              float* __restrict__ edge,
                                              float* __restrict__ acc) {
    int idx = blockIdx.x * 256 + threadIdx.x;
    int b = idx / NP, pos = idx - b * NP;
    int h = pos / HW, w = pos - h * HW;
    int wn = (w < HW - 1) ? w : HW - 2;
    int hn = (h < HW - 1) ? h : HW - 2;
    const float* pb = pe + (size_t)b * EMBD * NP;
    float sx = 0.f, sy = 0.f;
#pragma unroll 4
    for (int e = 0; e < EMBD; ++e) {
        const float* p = pb + (size_t)e * NP;
        sx += fabsf(p[h * HW + wn] - p[h * HW + wn + 1]);
        sy += fabsf(p[hn * HW + w] - p[hn * HW + HW + w]);
    }
    float ev = (sx + sy) * (0.5f / 32.0f);
    edge[idx] = ev;
    float tot = block_reduce_sum(ev);
    if (threadIdx.x == 0) atomicAdd(acc, tot);
}

__global__ void k_smooth(const float* __restrict__ sin_, const float* __restrict__ edge,
                         const float* __restrict__ acc, float* __restrict__ sout) {
    int idx = blockIdx.x * 256 + threadIdx.x;
    int pos = idx % NP;
    int bp = idx / NP;
    int b = bp >> 6;
    int h = pos / HW, w = pos - h * HW;
    float mean = acc[0] * (1.0f / 100352.0f);
    float m = (edge[(size_t)b * NP + pos] > mean) ? 1.f : 0.f;
    const float* sc = sin_ + (size_t)bp * NP;
    float s = 0.f;
#pragma unroll
    for (int dy = -1; dy <= 1; ++dy) {
        int yy = h + dy;
        if (yy < 0 || yy >= HW) continue;
#pragma unroll
        for (int dx = -1; dx <= 1; ++dx) {
            int xx = w + dx;
            if (xx < 0 || xx >= HW) continue;
            s += sc[yy * HW + xx];
        }
    }
    float c = sc[pos];
    sout[idx] = m * c + (1.f - m) * (s * (1.0f / 9.0f));
}

__global__ __launch_bounds__(256) void k_entropy(const float* __restrict__ sim,
                                                 float* __restrict__ acc) {
    int idx = blockIdx.x * 256 + threadIdx.x;
    int b = idx / NP, pos = idx - b * NP;
    const float* s = sim + (size_t)b * NPROTO * NP + pos;
    float v[NPROTO];
    float mx = -3.0e38f;
#pragma unroll
    for (int q = 0; q < NPROTO; ++q) { v[q] = s[(size_t)q * NP]; mx = fmaxf(mx, v[q]); }
    float sum = 0.f;
#pragma unroll
    for (int q = 0; q < NPROTO; ++q) { float e = expf(v[q] - mx); v[q] = e; sum += e; }
    float inv = 1.f / sum;
    float ent = 0.f;
#pragma unroll
    for (int q = 0; q < NPROTO; ++q) {
        float a = v[q] * inv;
        ent -= a * logf(a + 1e-8f);
    }
    float tot = block_reduce_sum(ent);
    if (threadIdx.x == 0) atomicAdd(acc + 1, tot);
}

__global__ void k_bb(const float* __restrict__ pb, const float* __restrict__ bs,
                     float* __restrict__ bbuf, float* __restrict__ obb) {
    int t = threadIdx.x;
    if (t < NPROTO) {
        float v = 1.f + tanhf(pb[t]) * bs[0];
        bbuf[t] = v;
        obb[t] = v;
        obb[NPROTO + t] = v;
    }
}

__global__ __launch_bounds__(256) void k_actsm(const float* __restrict__ sim,
                                               const float* __restrict__ bb,
                                               float* __restrict__ act,
                                               float* __restrict__ bgain) {
    int idx = blockIdx.x * 256 + threadIdx.x;
    int b = idx / NP, pos = idx - b * NP;
    const float* s = sim + (size_t)b * NPROTO * NP + pos;
    float v[NPROTO];
    float mx = -3.0e38f;
#pragma unroll
    for (int q = 0; q < NPROTO; ++q) { v[q] = s[(size_t)q * NP]; mx = fmaxf(mx, v[q]); }
    float sum = 0.f;
#pragma unroll
    for (int q = 0; q < NPROTO; ++q) { float e = expf(v[q] - mx); v[q] = e; sum += e; }
    float inv = 1.f / sum;
    float* a = act + (size_t)b * NPROTO * NP + pos;
    float bg = 0.f;
#pragma unroll
    for (int q = 0; q < NPROTO; ++q) {
        float p = v[q] * inv;
        a[(size_t)q * NP] = p;
        bg = fmaf(p, bb[q], bg);
    }
    bgain[idx] = bg;
}

__global__ void k_headprep(const float* __restrict__ w1, const float* __restrict__ b1,
                           const float* __restrict__ g1, const float* __restrict__ be1,
                           const float* __restrict__ m1, const float* __restrict__ v1,
                           const float* __restrict__ w2, const float* __restrict__ b2,
                           const float* __restrict__ g2, const float* __restrict__ be2,
                           const float* __restrict__ m2, const float* __restrict__ v2,
                           float* __restrict__ wf) {
    int oc = blockIdx.x * 256 + threadIdx.x;
    if (oc >= 512) return;
    float s1 = g1[oc] * rsqrtf(v1[oc] + 1e-5f);
#pragma unroll
    for (int k = 0; k < 9; ++k) wf[oc * 9 + k] = w1[oc * 9 + k] * s1;
    wf[41472 + oc] = (b1[oc] - m1[oc]) * s1 + be1[oc];
    float s2 = g2[oc] * rsqrtf(v2[oc] + 1e-5f);
    int g = oc >> 3, j = oc & 7;
#pragma unroll
    for (int icc = 0; icc < 8; ++icc)
#pragma unroll
        for (int k = 0; k < 9; ++k)
            wf[4608 + (size_t)g * 576 + icc * 72 + j * 9 + k] = w2[((size_t)oc * 8 + icc) * 9 + k] * s2;
    wf[41984 + oc] = (b2[oc] - m2[oc]) * s2 + be2[oc];
}

// fused 3-layer grouped heads, 16x16 out-tile. Stage2/3 compute pixel PAIRS
// with f32x2 packed FMA; even LDS row strides (24/22/18) keep pairs aligned.
__global__ __launch_bounds__(256) void k_heads(
    const float* __restrict__ act, const float* __restrict__ wf,
    const float* __restrict__ w3, const float* __restrict__ b3,
    float* __restrict__ res) {
    __shared__ float sA[22 * 24];           // origin (oy0-3, ox0-3), stride 24
    __shared__ float sH1[8][20 * 22];       // origin (oy0-2, ox0-2), stride 22
    __shared__ float sH2[8][18 * 18];       // origin (oy0-1, ox0-1), stride 18
    int tid = threadIdx.x;
    int tile = blockIdx.x, g = blockIdx.y, b = blockIdx.z;
    int oy0 = (tile / 14) * 16, ox0 = (tile % 14) * 16;
    const float* ain = act + (size_t)(b * NPROTO + g) * NP;

    for (int i = tid; i < 484; i += 256) {
        int y = i / 22, x = i - y * 22;
        int gy = oy0 - 3 + y, gx = ox0 - 3 + x;
        float v = 0.f;
        if ((unsigned)gy < HW && (unsigned)gx < HW) v = ain[gy * HW + gx];
        sA[y * 24 + x] = v;
    }
    __syncthreads();

    // stage1: 20x20, 1 px/thread
    const float* b1f = wf + 41472 + g * 8;
    for (int i = tid; i < 400; i += 256) {
        int y = i / 20, x = i - y * 20;
        int gy = oy0 - 2 + y, gx = ox0 - 2 + x;
        float keep = ((unsigned)gy < HW && (unsigned)gx < HW) ? 1.f : 0.f;
        const float* s0 = sA + y * 24 + x;
        float r0 = s0[0],  r1 = s0[1],  r2 = s0[2];
        float r3 = s0[24], r4 = s0[25], r5 = s0[26];
        float r6 = s0[48], r7 = s0[49], r8 = s0[50];
#pragma unroll
        for (int j = 0; j < 8; ++j) {
            const float* w = wf + (g * 8 + j) * 9;
            float v = fmaf(r0, w[0], fmaf(r1, w[1], fmaf(r2, w[2],
                      fmaf(r3, w[3], fmaf(r4, w[4], fmaf(r5, w[5],
                      fmaf(r6, w[6], fmaf(r7, w[7], fmaf(r8, w[8], b1f[j])))))))));
            sH1[j][y * 22 + x] = fmaxf(v, 0.f) * keep;
        }
    }
    __syncthreads();

    // stage2: 18x18 as 18x9 pixel pairs, f32x2 packed
    const float* w2f = wf + 4608 + (size_t)g * 576;
    const float* b2f = wf + 41984 + g * 8;
    if (tid < 162) {
        int y2 = tid / 9, xp = (tid - y2 * 9) * 2;
        f32x2 a2[8];
#pragma unroll
        for (int j = 0; j < 8; ++j) { float bv = b2f[j]; a2[j] = (f32x2){bv, bv}; }
#pragma unroll
        for (int icc = 0; icc < 8; ++icc) {
            const float* s0 = &sH1[icc][y2 * 22 + xp];
            f32x2 t[9];
#pragma unroll
            for (int r = 0; r < 3; ++r) {
                float f0 = s0[r * 22], f1 = s0[r * 22 + 1];
                float f2 = s0[r * 22 + 2], f3 = s0[r * 22 + 3];
                t[r * 3 + 0] = (f32x2){f0, f1};
                t[r * 3 + 1] = (f32x2){f1, f2};
                t[r * 3 + 2] = (f32x2){f2, f3};
            }
            const float* wr = w2f + icc * 72;
#pragma unroll
            for (int j = 0; j < 8; ++j) {
                const float* wj = wr + j * 9;
#pragma unroll
                for (int k = 0; k < 9; ++k) {
                    float wv = wj[k];
                    a2[j] = __builtin_elementwise_fma(t[k], (f32x2){wv, wv}, a2[j]);
                }
            }
        }
        int gy = oy0 - 1 + y2;
        int gx0 = ox0 - 1 + xp;
        float k0 = ((unsigned)gy < HW && (unsigned)gx0 < HW) ? 1.f : 0.f;
        float k1 = ((unsigned)gy < HW && (unsigned)(gx0 + 1) < HW) ? 1.f : 0.f;
        f32x2 kp = (f32x2){k0, k1};
        const f32x2 z2 = (f32x2){0.f, 0.f};
#pragma unroll
        for (int j = 0; j < 8; ++j) {
            f32x2 v = __builtin_elementwise_max(a2[j], z2) * kp;
            sH2[j][y2 * 18 + xp] = v.x;
            sH2[j][y2 * 18 + xp + 1] = v.y;
        }
    }
    __syncthreads();

    // stage3: 16x16 as 16x8 pairs, f32x2 packed
    if (tid < 128) {
        int y3 = tid >> 3, xp = (tid & 7) * 2;
        float bv = b3[g];
        f32x2 a2 = (f32x2){bv, bv};
#pragma unroll
        for (int icc = 0; icc < 8; ++icc) {
            const float* s0 = &sH2[icc][y3 * 18 + xp];
            const float* w = w3 + (size_t)(g * 8 + icc) * 9;
#pragma unroll
            for (int r = 0; r < 3; ++r) {
                float f0 = s0[r * 18], f1 = s0[r * 18 + 1];
                float f2 = s0[r * 18 + 2], f3 = s0[r * 18 + 3];
                float w0 = w[r * 3], w1 = w[r * 3 + 1], w2v = w[r * 3 + 2];
                a2 = __builtin_elementwise_fma((f32x2){f0, f1}, (f32x2){w0, w0}, a2);
                a2 = __builtin_elementwise_fma((f32x2){f1, f2}, (f32x2){w1, w1}, a2);
                a2 = __builtin_elementwise_fma((f32x2){f2, f3}, (f32x2){w2v, w2v}, a2);
            }
        }
        float* rp = res + (size_t)(b * NPROTO + g) * NP + (size_t)(oy0 + y3) * HW + (ox0 + xp);
        rp[0] = a2.x;
        rp[1] = a2.y;
    }
}

__global__ __launch_bounds__(256) void k_final(const float* __restrict__ act,
                                               const float* __restrict__ res,
                                               const float* __restrict__ bgain,
                                               const float* __restrict__ rscale,
                                               float* __restrict__ owt,
                                               float* __restrict__ oibm) {
    int idx = blockIdx.x * 256 + threadIdx.x;
    int b = idx / NP, pos = idx - b * NP;
    const float* a = act + (size_t)b * NPROTO * NP + pos;
    const float* r = res + (size_t)b * NPROTO * NP + pos;
    float wt = 0.f;
#pragma unroll
    for (int q = 0; q < NPROTO; ++q) wt = fmaf(a[(size_t)q * NP], r[(size_t)q * NP], wt);
    owt[idx] = wt;
    float gn = bgain[idx] * (1.f + tanhf(wt) * rscale[0]);
    gn = fminf(fmaxf(gn, 0.5f), 2.0f);
    oibm[idx] = gn;
}

__global__ void k_entfinal(const float* __restrict__ acc, float* __restrict__ o) {
    if (threadIdx.x == 0) o[0] = acc[1] * (1.0f / 100352.0f);
}

// ======================================================================
extern "C" void kernel_launch(void* const* d_in, const int* in_sizes, int n_in,
                              void* d_out, int out_size, void* d_ws, size_t ws_size,
                              hipStream_t stream) {
    const float* tokens[4] = {(const float*)d_in[0], (const float*)d_in[1],
                              (const float*)d_in[2], (const float*)d_in[3]};
    const float* proj_w[4] = {(const float*)d_in[4], (const float*)d_in[6],
                              (const float*)d_in[8], (const float*)d_in[10]};
    const float* proj_b[4] = {(const float*)d_in[5], (const float*)d_in[7],
                              (const float*)d_in[9], (const float*)d_in[11]};
    const float* up_w0 = (const float*)d_in[12]; const float* up_b0 = (const float*)d_in[13];
    const float* up_w1 = (const float*)d_in[14]; const float* up_b1 = (const float*)d_in[15];
    const float* down_w3 = (const float*)d_in[16]; const float* down_b3 = (const float*)d_in[17];
    const float* fuse_w = (const float*)d_in[18]; const float* fuse_b = (const float*)d_in[19];
    const float* pe_w1 = (const float*)d_in[20]; const float* pe_b1 = (const float*)d_in[21];
    const float* pe_bn_g = (const float*)d_in[22]; const float* pe_bn_b = (const float*)d_in[23];
    const float* pe_bn_m = (const float*)d_in[24]; const float* pe_bn_v = (const float*)d_in[25];
    const float* pe_w2 = (const float*)d_in[26]; const float* pe_b2 = (const float*)d_in[27];
    const float* prototypes = (const float*)d_in[28];
    const float* proto_biases = (const float*)d_in[29];
    const float* bias_scale = (const float*)d_in[30];
    const float* smooth_w = (const float*)d_in[31]; const float* smooth_b = (const float*)d_in[32];
    const float* hw1 = (const float*)d_in[33]; const float* hb1 = (const float*)d_in[34];
    const float* hg1 = (const float*)d_in[35]; const float* hbe1 = (const float*)d_in[36];
    const float* hm1 = (const float*)d_in[37]; const float* hv1 = (const float*)d_in[38];
    const float* hw2 = (const float*)d_in[39]; const float* hb2 = (const float*)d_in[40];
    const float* hg2 = (const float*)d_in[41]; const float* hbe2 = (const float*)d_in[42];
    const float* hm2 = (const float*)d_in[43]; const float* hv2 = (const float*)d_in[44];
    const float* hw3 = (const float*)d_in[45]; const float* hb3 = (const float*)d_in[46];
    const float* rscale = (const float*)d_in[47];
    (void)in_sizes; (void)n_in; (void)out_size; (void)ws_size;

    float* ws = (float*)d_ws;
    float* FEATS[4] = {ws + OFF_FEATS0, ws + OFF_FEATS1, ws + OFF_FEATS2, ws + OFF_FEATS3};
    float* TOKT = ws + OFF_TOKT;
    float* F0 = ws + OFF_F0; float* F1 = ws + OFF_F1; float* F3 = ws + OFF_F3;
    short* FUSEDBF = (short*)(ws + OFF_FUSEDBF);
    short* P64C = (short*)(ws + OFF_P64C);
    short* P224C = (short*)(ws + OFF_P224C);
    short* WB = (short*)(ws + OFF_WB);
    short* WFUSE = (short*)(ws + OFF_WFUSE);
    float* SHIFT = ws + OFF_SHIFT;
    float* T1 = ws + OFF_T1;
    float* SIMA = ws + OFF_SIMA; float* SIMB = ws + OFF_SIMB;
    float* EDGE = ws + OFF_EDGE; float* RES = ws + OFF_RES;
    float* BGAIN = ws + OFF_BGAIN; float* BBUF = ws + OFF_BB; float* ACC = ws + OFF_ACC;
    float* WF = ws + OFF_WF;

    float* out = (float*)d_out;
    float* o_ibm = out + O_IBM; float* o_act = out + O_ACT; float* o_bb = out + O_BB;
    float* o_wt = out + O_WT; float* o_pe = out + O_PE; float* o_ent = out + O_ENT;

    const int OCH[4] = {256, 512, 1024, 1024};
    for (int s = 0; s < 4; ++s)
        k_transpose<<<768, 256, 0, stream>>>(tokens[s], TOKT + s * 196608);
    for (int s = 0; s < 4; ++s)
        k_proj<<<dim3(OCH[s], BATCH), 256, 0, stream>>>(TOKT + s * 196608, proj_w[s], proj_b[s],
                                                        FEATS[s], OCH[s]);
    k_convt<<<dim3(16, 256, BATCH), 256, 0, stream>>>(FEATS[0], up_w0, up_b0, F0, 256, 256, 4);
    k_convt<<<dim3(4, 512, BATCH), 256, 0, stream>>>(FEATS[1], up_w1, up_b1, F1, 512, 512, 2);
    k_down<<<dim3(1024, BATCH), 256, 0, stream>>>(FEATS[3], down_w3, down_b3, F3);
    k_wfuseprep<<<2816, 256, 0, stream>>>(fuse_w, WFUSE);
    k_fusedcat_bf<<<90112, 256, 0, stream>>>(F0, F1, FEATS[2], F3, FUSEDBF);
    k_fuse_mfma<<<512, 256, 0, stream>>>(FUSEDBF, (const bf16x8*)WFUSE, fuse_b, P64C);
    // FUSEDBF dead: WB/SHIFT (inside its range) safe now
    k_w1prep<<<1152, 256, 0, stream>>>(pe_w1, pe_b1, pe_bn_g, pe_bn_b, pe_bn_m, pe_bn_v,
                                       WB, SHIFT);
    k_resize224bf2<<<12544, 256, 0, stream>>>(P64C, P224C);
    k_conv1mfma<<<dim3(392, BATCH), 256, 0, stream>>>(P224C, (const bf16x8*)WB, SHIFT, T1);
    k_conv3<4, false, false><<<dim3(49, 8, BATCH), 256, 0, stream>>>(
        T1, pe_w2, pe_b2, nullptr, nullptr, nullptr, nullptr, o_pe, 128, 32);
    k_sim<<<392, 256, 0, stream>>>(o_pe, prototypes, SIMA);
    k_init<<<1, 64, 0, stream>>>(ACC);
    k_edge<<<392, 256, 0, stream>>>(o_pe, EDGE, ACC);
    k_smooth<<<25088, 256, 0, stream>>>(SIMA, EDGE, ACC, SIMB);
    k_smooth<<<25088, 256, 0, stream>>>(SIMB, EDGE, ACC, SIMA);
    k_entropy<<<392, 256, 0, stream>>>(SIMA, ACC);
    k_conv3<8, false, false><<<dim3(49, 8, BATCH), 256, 0, stream>>>(
        SIMA, smooth_w, smooth_b, nullptr, nullptr, nullptr, nullptr, SIMB, 64, 64);
    k_bb<<<1, 64, 0, stream>>>(proto_biases, bias_scale, BBUF, o_bb);
    k_actsm<<<392, 256, 0, stream>>>(SIMB, BBUF, o_act, BGAIN);
    k_headprep<<<2, 256, 0, stream>>>(hw1, hb1, hg1, hbe1, hm1, hv1,
                                      hw2, hb2, hg2, hbe2, hm2, hv2, WF);
    k_heads<<<dim3(196, 64, BATCH), 256, 0, stream>>>(o_act, WF, hw3, hb3, RES);
    k_final<<<392, 256, 0, stream>>>(o_act, RES, BGAIN, rscale, o_wt, o_ibm);
    k_entfinal<<<1, 1, 0, stream>>>(ACC, o_ent);
}